// Round 19
// baseline (225.438 us; speedup 1.0000x reference)
//
#include <hip/hip_runtime.h>
#include <hip/hip_bf16.h>
#include <math.h>

#define DEV __device__ __forceinline__

constexpr int B = 8, N = 1024, DIN = 256, H = 4, DATT = 64, DV = 64;
constexpr int BN = B * N;             // 8192
constexpr int HD = H * DATT;          // 256
constexpr int HDV = H * DV;           // 256
constexpr int COLS = HD + HDV;        // 512
constexpr int BHN = B * H * N;        // 32768
constexpr float EPSF = 1e-7f;

using short8 = __attribute__((ext_vector_type(8))) short;
using f32x4  = __attribute__((ext_vector_type(4))) float;

DEV unsigned short f2bf(float f) {
    __hip_bfloat16 h = __float2bfloat16(f);
    return *reinterpret_cast<unsigned short*>(&h);
}
DEV float bfu2f(unsigned short u) { return __uint_as_float(((unsigned)u) << 16); }

// truncation hi/lo split: hi=trunc16(v) (exact residual), lo=trunc16(v-hi)
DEV void tsplit(float v, short& hs, short& ls) {
    unsigned vu = __float_as_uint(v);
    float lo = v - __uint_as_float(vu & 0xFFFF0000u);
    hs = (short)(unsigned short)(vu >> 16);
    ls = (short)(unsigned short)(__float_as_uint(lo) >> 16);
}

// ---------------- K1: logmap0 row scale: s = artanh(nc)/nc ----------------
__global__ void k_scale(const float* __restrict__ x, float* __restrict__ s) {
    int p = blockIdx.x * 4 + (threadIdx.x >> 6);
    int l = threadIdx.x & 63;
    const float4* xr = reinterpret_cast<const float4*>(x + (size_t)p * DIN);
    float4 u = xr[l];
    float ss = u.x * u.x + u.y * u.y + u.z * u.z + u.w * u.w;
    for (int m = 32; m; m >>= 1) ss += __shfl_xor(ss, m);
    if (l == 0) {
        float n = sqrtf(ss);
        n = fminf(fmaxf(n, EPSF), 1.0f - 1e-5f);
        float at = 0.5f * __logf((1.f + n) / (1.f - n));
        s[p] = at / n;
    }
}

// ---------------- K0: build Wcat [256][512] f32 (Wq | Wv) ----------------
__global__ void k_wcat(const float* __restrict__ Wq, const float* __restrict__ Wv,
                       float* __restrict__ Wc) {
    int idx = blockIdx.x * 256 + threadIdx.x;   // < 256*512
    int k = idx >> 9, c = idx & 511;
    int cc = c & 255;
    int h = cc >> 6, e = cc & 63;
    const float* src = (c < HD) ? Wq : Wv;
    Wc[idx] = src[(h * DIN + k) * 64 + e];
}

// ---------------- K2: GEMM h_all[8192][512] = (s*x)[8192][256] @ Wc ----------------
__global__ __launch_bounds__(256) void k_gemm(const float* __restrict__ x,
                                              const float* __restrict__ s,
                                              const float* __restrict__ Wc,
                                              float* __restrict__ hall) {
    __shared__ float As[16][68];
    __shared__ float Bs[16][68];
    int bm = blockIdx.x, bn = blockIdx.y;
    int tid = threadIdx.x;
    int ty = tid >> 4, tx = tid & 15;
    float acc[4][4] = {};
    int rowbase = bm * 64, colbase = bn * 64;
    int am = tid >> 2;
    int ak = (tid & 3) * 4;
    float sc = s[rowbase + am];
    for (int kt = 0; kt < DIN; kt += 16) {
        float4 u = *reinterpret_cast<const float4*>(x + (size_t)(rowbase + am) * DIN + kt + ak);
        As[ak + 0][am] = u.x * sc;
        As[ak + 1][am] = u.y * sc;
        As[ak + 2][am] = u.z * sc;
        As[ak + 3][am] = u.w * sc;
        int bk = tid >> 4, bc = (tid & 15) * 4;
        float4 w4 = *reinterpret_cast<const float4*>(Wc + (size_t)(kt + bk) * COLS + colbase + bc);
        *reinterpret_cast<float4*>(&Bs[bk][bc]) = w4;
        __syncthreads();
        for (int k = 0; k < 16; k++) {
            float4 a4 = *reinterpret_cast<const float4*>(&As[k][ty * 4]);
            float4 b4 = *reinterpret_cast<const float4*>(&Bs[k][tx * 4]);
            float av[4] = {a4.x, a4.y, a4.z, a4.w};
            float bv[4] = {b4.x, b4.y, b4.z, b4.w};
            for (int i = 0; i < 4; i++)
                for (int j = 0; j < 4; j++) acc[i][j] = fmaf(av[i], bv[j], acc[i][j]);
        }
        __syncthreads();
    }
    for (int i = 0; i < 4; i++) {
        float4 o = make_float4(acc[i][0], acc[i][1], acc[i][2], acc[i][3]);
        *reinterpret_cast<float4*>(hall + (size_t)(rowbase + ty * 4 + i) * COLS + colbase + tx * 4) = o;
    }
}

// ---------------- K2c: hall -> hallT transpose+convert, FUSED with es/ed dots --------
__global__ __launch_bounds__(256) void k_hT(const float* __restrict__ hall,
        const float* __restrict__ aqs, const float* __restrict__ aqd,
        const float* __restrict__ avs, const float* __restrict__ avd,
        unsigned short* __restrict__ hallT, float* __restrict__ esq,
        float* __restrict__ edq, float* __restrict__ esv, float* __restrict__ edv) {
    int jt = blockIdx.x, h = blockIdx.y, b = blockIdx.z;   // 16,4,8
    __shared__ float T[64][69];
    int t = threadIdx.x;
    int bh = b * H + h;
    int jl = t >> 2, cg = t & 3;         // load + dot: row jl, col-chunk cg*16
    int el = t >> 2, seg = t & 3;        // store: e-row el, j-chunk seg*16
    #pragma unroll
    for (int pass = 0; pass < 2; pass++) {
        int colbase = (pass == 0) ? h * 64 : 256 + h * 64;
        const float* as = (pass == 0) ? aqs : avs;
        const float* ad = (pass == 0) ? aqd : avd;
        float* es = (pass == 0) ? esq : esv;
        float* ed = (pass == 0) ? edq : edv;
        __syncthreads();                 // WAR vs previous pass
        {
            const float* src = hall + (size_t)(b * N + jt * 64 + jl) * COLS + colbase + cg * 16;
            #pragma unroll
            for (int u = 0; u < 4; u++) {
                float4 v = *reinterpret_cast<const float4*>(src + u * 4);
                T[jl][cg * 16 + u * 4 + 0] = v.x;
                T[jl][cg * 16 + u * 4 + 1] = v.y;
                T[jl][cg * 16 + u * 4 + 2] = v.z;
                T[jl][cg * 16 + u * 4 + 3] = v.w;
            }
        }
        __syncthreads();
        {   // transposed bf16 store
            unsigned int pk[8];
            #pragma unroll
            for (int k = 0; k < 8; k++) {
                float f0 = T[seg * 16 + 2 * k][el];
                float f1 = T[seg * 16 + 2 * k + 1][el];
                pk[k] = (unsigned)f2bf(f0) | ((unsigned)f2bf(f1) << 16);
            }
            unsigned short* dst = hallT + ((size_t)(bh * 128 + pass * 64 + el)) * 1024
                                  + jt * 64 + seg * 16;
            *reinterpret_cast<uint4*>(dst)     = make_uint4(pk[0], pk[1], pk[2], pk[3]);
            *reinterpret_cast<uint4*>(dst + 8) = make_uint4(pk[4], pk[5], pk[6], pk[7]);
        }
        {   // es/ed dots: 4 lanes per row, 16 elems each, 2-step shfl reduce
            float p1 = 0.f, p2 = 0.f;
            #pragma unroll
            for (int u = 0; u < 16; u++) {
                float hv = T[jl][cg * 16 + u];
                p1 = fmaf(hv, as[h * 64 + cg * 16 + u], p1);
                p2 = fmaf(hv, ad[h * 64 + cg * 16 + u], p2);
            }
            p1 += __shfl_xor(p1, 1); p2 += __shfl_xor(p2, 1);
            p1 += __shfl_xor(p1, 2); p2 += __shfl_xor(p2, 2);
            if (cg == 0) {
                es[(size_t)bh * N + jt * 64 + jl] = p1;
                ed[(size_t)bh * N + jt * 64 + jl] = p2;
            }
        }
    }
}

// ---------------- K3a: softmax stats, h-merged (adj read ONCE per (b,i)) ----------
__global__ void k_stats(const float* __restrict__ adj, const float* __restrict__ esq,
                        const float* __restrict__ edq, const float* __restrict__ esv,
                        const float* __restrict__ edv, float* __restrict__ stats,
                        unsigned char* __restrict__ amask) {
    int pid = blockIdx.x;                 // b*N + i
    int b = pid >> 10, i = pid & 1023;
    int t = threadIdx.x;                  // 128 threads, 8 j each
    const float* arow = adj + (size_t)pid * N + t * 8;
    float4 a0 = *reinterpret_cast<const float4*>(arow);
    float4 a1 = *reinterpret_cast<const float4*>(arow + 4);
    float am[8] = {a0.x, a0.y, a0.z, a0.w, a1.x, a1.y, a1.z, a1.w};
    unsigned mb = 0;
    #pragma unroll
    for (int j = 0; j < 8; j++) mb |= (unsigned)(am[j] > 0.f) << j;
    amask[(size_t)pid * 128 + t] = (unsigned char)mb;

    __shared__ float red[2][2];
    __shared__ float red2[2][2];
    int w = t >> 6;
    for (int h = 0; h < H; h++) {
        int bh = b * H + h;
        float esqi = esq[(size_t)bh * N + i], esvi = esv[(size_t)bh * N + i];
        const float* edqr = edq + (size_t)bh * N + t * 8;
        const float* edvr = edv + (size_t)bh * N + t * 8;
        float4 q0 = *reinterpret_cast<const float4*>(edqr);
        float4 q1 = *reinterpret_cast<const float4*>(edqr + 4);
        float4 w0 = *reinterpret_cast<const float4*>(edvr);
        float4 w1 = *reinterpret_cast<const float4*>(edvr + 4);
        float edqv[8] = {q0.x, q0.y, q0.z, q0.w, q1.x, q1.y, q1.z, q1.w};
        float edvv[8] = {w0.x, w0.y, w0.z, w0.w, w1.x, w1.y, w1.z, w1.w};
        float eq[8], ev[8];
        float mq = -1e30f, mv = -1e30f;
        #pragma unroll
        for (int j = 0; j < 8; j++) {
            bool msk = (mb >> j) & 1;
            float q = esqi + edqv[j]; q = fmaxf(q, 0.2f * q);
            float v = esvi + edvv[j]; v = fmaxf(v, 0.2f * v);
            eq[j] = msk ? q : -1e30f;
            ev[j] = msk ? v : -1e30f;
            mq = fmaxf(mq, eq[j]); mv = fmaxf(mv, ev[j]);
        }
        for (int m = 32; m; m >>= 1) { mq = fmaxf(mq, __shfl_xor(mq, m)); mv = fmaxf(mv, __shfl_xor(mv, m)); }
        if ((t & 63) == 0) { red[w][0] = mq; red[w][1] = mv; }
        __syncthreads();
        mq = fmaxf(red[0][0], red[1][0]);
        mv = fmaxf(red[0][1], red[1][1]);
        float sq_ = 0.f, sv_ = 0.f;
        #pragma unroll
        for (int j = 0; j < 8; j++) { sq_ += __expf(eq[j] - mq); sv_ += __expf(ev[j] - mv); }
        for (int m = 32; m; m >>= 1) { sq_ += __shfl_xor(sq_, m); sv_ += __shfl_xor(sv_, m); }
        if ((t & 63) == 0) { red2[w][0] = sq_; red2[w][1] = sv_; }
        __syncthreads();
        if (t == 0) {
            int bid = bh * N + i;
            stats[bid] = mq;
            stats[BHN + bid] = red2[0][0] + red2[1][0];
            stats[2 * BHN + bid] = mv;
            stats[3 * BHN + bid] = red2[0][1] + red2[1][1];
        }
        __syncthreads();                  // WAR: red/red2 reused next h
    }
}

// ---------------- K3b: MFMA GAT aggregation; exp2-folded + trunc-packed weights ------
__global__ __launch_bounds__(512) void k_aggr(const unsigned char* __restrict__ amask,
        const unsigned short* __restrict__ hallT, const float* __restrict__ esq,
        const float* __restrict__ edq, const float* __restrict__ esv,
        const float* __restrict__ edv, const float* __restrict__ stats,
        float* __restrict__ outq, float* __restrict__ outv) {
    int f = blockIdx.x;
    int g = ((f & 7) << 7) | (f >> 3);        // bijective: 1024 = 8 x 128
    int b = g >> 7;
    int it = (g >> 2) & 31;
    int h = g & 3;
    int bh = b * H + h;
    int i0 = it * 32;
    int t = threadIdx.x;
    int lane = t & 63, wv = t >> 6;           // 0..7
    int team = wv >> 1;                       // j-quarter 0..3
    int mh = wv & 1;                          // i-half

    int i = i0 + mh * 16 + (lane & 15);
    int bi = bh * N + i;
    constexpr float L2E = 1.44269504f;
    float esq_i = esq[bi], esv_i = esv[bi];
    // w = exp((q-m))/sum  ==  exp2(q*L2E + c), c = -(m*L2E + log2(sum))
    float cq2 = -fmaf(stats[bi],           L2E, __builtin_amdgcn_logf(stats[BHN + bi]));
    float cv2 = -fmaf(stats[2 * BHN + bi], L2E, __builtin_amdgcn_logf(stats[3 * BHN + bi]));
    const unsigned char* mrow = amask + (size_t)(b * N + i) * 128;
    const float* edqrow = edq + (size_t)bh * N;
    const float* edvrow = edv + (size_t)bh * N;
    int klo = lane >> 4;
    const unsigned short* bbq = hallT
        + ((size_t)(bh * 128 + (lane & 15))) * 1024 + klo * 8;
    const unsigned short* bbv = bbq + (size_t)64 * 1024;

    f32x4 accq[4] = {}, accv[4] = {};
    int jbase = team * 256;
    for (int jj = 0; jj < 8; jj++) {
        int j0 = jbase + jj * 32;
        unsigned mword = *reinterpret_cast<const unsigned*>(mrow + (j0 >> 3));
        float4 q0 = *reinterpret_cast<const float4*>(edqrow + j0 + klo * 8);
        float4 q1 = *reinterpret_cast<const float4*>(edqrow + j0 + klo * 8 + 4);
        float4 v0 = *reinterpret_cast<const float4*>(edvrow + j0 + klo * 8);
        float4 v1 = *reinterpret_cast<const float4*>(edvrow + j0 + klo * 8 + 4);
        float eq[8] = {q0.x, q0.y, q0.z, q0.w, q1.x, q1.y, q1.z, q1.w};
        float ev[8] = {v0.x, v0.y, v0.z, v0.w, v1.x, v1.y, v1.z, v1.w};
        union { uint4 u4; short8 s8; } pq_, pv_;
        unsigned* uq = reinterpret_cast<unsigned*>(&pq_.u4);
        unsigned* uv = reinterpret_cast<unsigned*>(&pv_.u4);
        #pragma unroll
        for (int pu = 0; pu < 4; pu++) {
            unsigned wq0, wq1, wv0, wv1;
            {
                int u = pu * 2;
                bool on = (mword >> (klo * 8 + u)) & 1;
                float q = esq_i + eq[u]; q = fmaxf(q, 0.2f * q);
                float v = esv_i + ev[u]; v = fmaxf(v, 0.2f * v);
                wq0 = on ? __float_as_uint(__builtin_amdgcn_exp2f(fmaf(q, L2E, cq2))) : 0u;
                wv0 = on ? __float_as_uint(__builtin_amdgcn_exp2f(fmaf(v, L2E, cv2))) : 0u;
            }
            {
                int u = pu * 2 + 1;
                bool on = (mword >> (klo * 8 + u)) & 1;
                float q = esq_i + eq[u]; q = fmaxf(q, 0.2f * q);
                float v = esv_i + ev[u]; v = fmaxf(v, 0.2f * v);
                wq1 = on ? __float_as_uint(__builtin_amdgcn_exp2f(fmaf(q, L2E, cq2))) : 0u;
                wv1 = on ? __float_as_uint(__builtin_amdgcn_exp2f(fmaf(v, L2E, cv2))) : 0u;
            }
            uq[pu] = (wq0 >> 16) | (wq1 & 0xFFFF0000u);   // trunc bf16 pair
            uv[pu] = (wv0 >> 16) | (wv1 & 0xFFFF0000u);
        }
        short8 afq = pq_.s8, afv = pv_.s8;
        #pragma unroll
        for (int nt = 0; nt < 4; nt++) {
            short8 bq = *reinterpret_cast<const short8*>(bbq + j0 + nt * 16384);
            accq[nt] = __builtin_amdgcn_mfma_f32_16x16x32_bf16(afq, bq, accq[nt], 0, 0, 0);
            short8 bv = *reinterpret_cast<const short8*>(bbv + j0 + nt * 16384);
            accv[nt] = __builtin_amdgcn_mfma_f32_16x16x32_bf16(afv, bv, accv[nt], 0, 0, 0);
        }
    }

    // 2-stage team combine: slots = (team>>1)*2 + mh, 4 x 8KB = 32KB
    __shared__ __align__(16) float red[8192];
    int slot = (team >> 1) * 2 + mh;
    float* buf = red + slot * 2048;
    __syncthreads();
    if (team & 1) {                           // teams 1,3 write
        #pragma unroll
        for (int k = 0; k < 4; k++) {
            *reinterpret_cast<f32x4*>(&buf[(k * 64 + lane) * 4])       = accq[k];
            *reinterpret_cast<f32x4*>(&buf[((k + 4) * 64 + lane) * 4]) = accv[k];
        }
    }
    __syncthreads();
    if (!(team & 1)) {                        // teams 0,2 add partner
        #pragma unroll
        for (int k = 0; k < 4; k++) {
            f32x4 pq = *reinterpret_cast<const f32x4*>(&buf[(k * 64 + lane) * 4]);
            f32x4 pv = *reinterpret_cast<const f32x4*>(&buf[((k + 4) * 64 + lane) * 4]);
            accq[k] += pq; accv[k] += pv;
        }
    }
    __syncthreads();
    if (team == 2) {                          // team 2 writes to slots 0,1
        float* d2 = red + mh * 2048;
        #pragma unroll
        for (int k = 0; k < 4; k++) {
            *reinterpret_cast<f32x4*>(&d2[(k * 64 + lane) * 4])       = accq[k];
            *reinterpret_cast<f32x4*>(&d2[((k + 4) * 64 + lane) * 4]) = accv[k];
        }
    }
    __syncthreads();
    if (team == 0) {
        float* s2 = red + mh * 2048;
        #pragma unroll
        for (int nt = 0; nt < 4; nt++) {
            f32x4 pq = *reinterpret_cast<const f32x4*>(&s2[(nt * 64 + lane) * 4]);
            f32x4 pv = *reinterpret_cast<const f32x4*>(&s2[((nt + 4) * 64 + lane) * 4]);
            #pragma unroll
            for (int r = 0; r < 4; r++) {
                int irow = i0 + mh * 16 + (lane >> 4) * 4 + r;
                int e = nt * 16 + (lane & 15);
                outq[(size_t)(b * N + irow) * 256 + h * 64 + e] = accq[nt][r] + pq[r];
                outv[(size_t)(b * N + irow) * 256 + h * 64 + e] = accv[nt][r] + pv[r];
            }
        }
    }
}

// ---------------- K4: expmap0; emits qh/ql (bf16 hi/lo), sq, isr, val ----------------
__global__ void k_expmap(const float* __restrict__ outq, const float* __restrict__ outv,
                         unsigned short* __restrict__ qh, unsigned short* __restrict__ ql,
                         float* __restrict__ sq, float* __restrict__ isr,
                         float* __restrict__ val) {
    int p = blockIdx.x, t = threadIdx.x;
    int h = t >> 6, e = t & 63;
    float v = outq[(size_t)p * HD + t];
    float ss = v * v;
    for (int m = 32; m; m >>= 1) ss += __shfl_xor(ss, m);
    float n = fmaxf(sqrtf(ss), EPSF);
    float tn = tanhf(n);
    float qv = v * (tn / n);
    short hs, ls; tsplit(qv, hs, ls);
    qh[((size_t)p << 8) + t] = (unsigned short)hs;
    ql[((size_t)p << 8) + t] = (unsigned short)ls;
    if (e == 0) {
        float s = tn * tn;
        sq[h * BN + p] = s;
        isr[h * BN + p] = __builtin_amdgcn_rcpf(1.f - s);
    }

    float vv = outv[(size_t)p * HDV + t];
    float s2 = vv * vv;
    for (int m = 32; m; m >>= 1) s2 += __shfl_xor(s2, m);
    __shared__ float part[4];
    if (e == 0) part[h] = s2;
    __syncthreads();
    float tot = part[0] + part[1] + part[2] + part[3];
    float nv = fmaxf(sqrtf(tot), EPSF);
    float sclv = tanhf(nv) / nv;
    val[(size_t)p * HDV + t] = vv * sclv;
}

// ---------------- K5: MFMA pair-dist, barrier-free; B-side hi-only (2 MFMA) --------
// reshape(-1,B,N,N) closed form: h=m2%4, m=(n2%4)*256+m2/4, n=(b2*256+n2/4)%1024, b=2a+b2/4
__global__ __launch_bounds__(256) void k_att(const unsigned short* __restrict__ qh,
        const unsigned short* __restrict__ ql, const float* __restrict__ sq,
        const float* __restrict__ isr, const float* __restrict__ rr,
        const float* __restrict__ tt, float* __restrict__ m_out) {
    int f = blockIdx.x;
    int g = ((f & 7) << 7) | (f >> 3);        // bijective 1024
    int b2 = g >> 7;
    int rem = g & 127;
    int c = rem >> 5, h = (rem >> 3) & 3, kc = (rem >> 1) & 3, xh = rem & 1;
    int t = threadIdx.x;
    int l = t & 63, w = t >> 6;
    int klo = l >> 4;

    int nstart = (b2 * 256 + kc * 64) & 1023;
    int mstart = c * 256 + xh * 128;

    float tacc[8][4] = {};

    #pragma unroll
    for (int a = 0; a < 4; a++) {
        int b = 2 * a + (b2 >> 2);
        size_t xbase = ((size_t)(b * N + nstart + w * 16 + (l & 15)) << 8) + h * 64 + klo * 8;
        short8 Ah[2], Al[2];
        #pragma unroll
        for (int kk = 0; kk < 2; kk++) {
            Ah[kk] = *reinterpret_cast<const short8*>(qh + xbase + kk * 32);
            Al[kk] = *reinterpret_cast<const short8*>(ql + xbase + kk * 32);
        }
        float ra = rr[a], ta = tt[a];
        float c1 = 2.f * ta;                       // ln2*log2e == 1
        float c0 = c1 * ra * 1.44269504f;          // 2*r*t*log2e
        float sxr[4], ixr[4];
        #pragma unroll
        for (int r = 0; r < 4; r++) {
            int gx = h * BN + b * N + nstart + w * 16 + (l >> 4) * 4 + r;
            sxr[r] = sq[gx];
            ixr[r] = 2.f * isr[gx];
        }
        size_t ybase = ((size_t)(b * N + mstart + (l & 15)) << 8) + h * 64 + klo * 8;
        #pragma unroll
        for (int nt = 0; nt < 8; nt++) {
            size_t yb = ybase + ((size_t)(nt * 16) << 8);
            f32x4 acc = {};
            #pragma unroll
            for (int kk = 0; kk < 2; kk++) {
                short8 Bh = *reinterpret_cast<const short8*>(qh + yb + kk * 32);
                acc = __builtin_amdgcn_mfma_f32_16x16x32_bf16(Ah[kk], Bh, acc, 0, 0, 0);
                acc = __builtin_amdgcn_mfma_f32_16x16x32_bf16(Al[kk], Bh, acc, 0, 0, 0);
            }
            int gy = h * BN + b * N + mstart + nt * 16 + (l & 15);
            float sy = sq[gy];
            float iy = isr[gy];
            #pragma unroll
            for (int r = 0; r < 4; r++) {
                float diff = fmaxf(fmaf(-2.f, acc[r], sxr[r] + sy), 0.f);
                float ixy = fminf(ixr[r] * iy, 2e7f);          // 2/max(den,1e-7)
                float z = fmaxf(fmaf(diff, ixy, 1.f), 1.f + EPSF);
                float s_ = z + __builtin_amdgcn_sqrtf(fmaf(z, z, -1.f));   // e^dist
                float l2 = __builtin_amdgcn_logf(s_);                      // log2
                float ex = __builtin_amdgcn_exp2f(fmaf(-c1, l2, c0));      // e^{2u}
                float rc = __builtin_amdgcn_rcpf(ex + 1.f);
                tacc[nt][r] += fmaf(-2.f, rc, 1.f);            // tanh(u), NaN-safe
            }
        }
    }
    // write-out (scrambled reshape positions)
    #pragma unroll
    for (int nt = 0; nt < 8; nt++) {
        #pragma unroll
        for (int r = 0; r < 4; r++) {
            int n_local = w * 16 + (l >> 4) * 4 + r;
            int n2 = c + 4 * (kc * 64 + n_local);
            int mloc = xh * 128 + nt * 16 + (l & 15);
            int m2 = 4 * mloc + h;
            m_out[((size_t)b2 << 20) + ((size_t)n2 << 10) + m2] = 0.25f * tacc[nt][r];
        }
    }
}

// ---------------- K6: in-place symmetrize on d_out att region ----------------
__global__ void k_sym(float* __restrict__ m) {
    int ti = blockIdx.x, tj = blockIdx.y, b = blockIdx.z;
    if (ti > tj) return;
    __shared__ float A[32][33], Bt[32][33];
    int t = threadIdx.x;
    int r = t >> 3, c4 = (t & 7) * 4;
    size_t baseA = ((size_t)b << 20) + (size_t)(ti * 32) * N + tj * 32;
    size_t baseB = ((size_t)b << 20) + (size_t)(tj * 32) * N + ti * 32;
    float4 ua = *reinterpret_cast<const float4*>(m + baseA + (size_t)r * N + c4);
    float4 ub = *reinterpret_cast<const float4*>(m + baseB + (size_t)r * N + c4);
    A[r][c4 + 0] = ua.x; A[r][c4 + 1] = ua.y; A[r][c4 + 2] = ua.z; A[r][c4 + 3] = ua.w;
    Bt[r][c4 + 0] = ub.x; Bt[r][c4 + 1] = ub.y; Bt[r][c4 + 2] = ub.z; Bt[r][c4 + 3] = ub.w;
    __syncthreads();
    for (int u = 0; u < 4; u++) {
        int cc = c4 + u;
        float oa = 0.5f * (A[r][cc] + Bt[cc][r]);
        float ob = 0.5f * (Bt[r][cc] + A[cc][r]);
        m[baseA + (size_t)r * N + cc] = oa;
        m[baseB + (size_t)r * N + cc] = ob;
    }
}

extern "C" void kernel_launch(void* const* d_in, const int* in_sizes, int n_in,
                              void* d_out, int out_size, void* d_ws, size_t ws_size,
                              hipStream_t stream) {
    const float* x   = (const float*)d_in[0];
    const float* adj = (const float*)d_in[1];
    const float* Wq  = (const float*)d_in[3];
    const float* aqs = (const float*)d_in[4];
    const float* aqd = (const float*)d_in[5];
    const float* Wv  = (const float*)d_in[6];
    const float* avs = (const float*)d_in[7];
    const float* avd = (const float*)d_in[8];
    const float* rr  = (const float*)d_in[9];
    const float* tt  = (const float*)d_in[10];

    float* ws = (float*)d_ws;
    float* s     = ws;                            // 8192
    float* Wc    = s + BN;                        // 131072 f32
    float* hall  = Wc + 256 * COLS;               // 4194304 f32 (16 MB)
    float* esq   = hall + (size_t)BN * COLS;      // 32768 x4
    float* edq   = esq + BHN;
    float* esv   = edq + BHN;
    float* edv   = esv + BHN;
    float* stats = edv + BHN;                     // 4*BHN
    float* outq  = stats + 4 * BHN;               // 2097152
    float* outv  = outq + (size_t)BN * HD;        // 2097152
    float* sq    = outv + (size_t)BN * HDV;       // 32768
    unsigned short* hallT = (unsigned short*)(sq + H * BN);   // BN*COLS bf16 = 8 MB
    unsigned char* amask = (unsigned char*)(hallT + (size_t)BN * COLS); // 1 MB
    size_t need = (size_t)((char*)(amask + (size_t)BN * 128) - (char*)ws);
    if (ws_size < need) return;                   // ws too small: bail visibly

    // qh/ql/isr alias the hall region (dead after k_hT reads it; k_expmap runs later)
    unsigned short* qh = (unsigned short*)hall;
    unsigned short* ql = qh + (size_t)BN * 256;
    float* isr = (float*)(ql + (size_t)BN * 256);

    float* val  = (float*)d_out;
    float* matt = (float*)d_out + (size_t)BN * HDV;

    k_scale<<<BN / 4, 256, 0, stream>>>(x, s);
    k_wcat<<<(256 * COLS) / 256, 256, 0, stream>>>(Wq, Wv, Wc);
    k_gemm<<<dim3(BN / 64, COLS / 64), 256, 0, stream>>>(x, s, Wc, hall);
    k_hT<<<dim3(16, H, B), 256, 0, stream>>>(hall, aqs, aqd, avs, avd,
                                             hallT, esq, edq, esv, edv);
    k_stats<<<BN, 128, 0, stream>>>(adj, esq, edq, esv, edv, stats, amask);
    k_aggr<<<1024, 512, 0, stream>>>(amask, hallT, esq, edq, esv, edv, stats, outq, outv);
    k_expmap<<<BN, 256, 0, stream>>>(outq, outv, qh, ql, sq, isr, val);
    k_att<<<1024, 256, 0, stream>>>(qh, ql, sq, isr, rr, tt, matt);
    k_sym<<<dim3(32, 32, 8), 256, 0, stream>>>(matt);
}

// Round 20
// 220.102 us; speedup vs baseline: 1.0242x; 1.0242x over previous
//
#include <hip/hip_runtime.h>
#include <hip/hip_bf16.h>
#include <math.h>

#define DEV __device__ __forceinline__

constexpr int B = 8, N = 1024, DIN = 256, H = 4, DATT = 64, DV = 64;
constexpr int BN = B * N;             // 8192
constexpr int HD = H * DATT;          // 256
constexpr int HDV = H * DV;           // 256
constexpr int COLS = HD + HDV;        // 512
constexpr int BHN = B * H * N;        // 32768
constexpr float EPSF = 1e-7f;

using short8 = __attribute__((ext_vector_type(8))) short;
using f32x4  = __attribute__((ext_vector_type(4))) float;

DEV unsigned short f2bf(float f) {
    __hip_bfloat16 h = __float2bfloat16(f);
    return *reinterpret_cast<unsigned short*>(&h);
}
DEV float bfu2f(unsigned short u) { return __uint_as_float(((unsigned)u) << 16); }

// truncation hi/lo split: hi=trunc16(v) (exact residual), lo=trunc16(v-hi)
DEV void tsplit(float v, short& hs, short& ls) {
    unsigned vu = __float_as_uint(v);
    float lo = v - __uint_as_float(vu & 0xFFFF0000u);
    hs = (short)(unsigned short)(vu >> 16);
    ls = (short)(unsigned short)(__float_as_uint(lo) >> 16);
}

// ---------------- K0: build Wcat [256][512] f32 (Wq | Wv) ----------------
__global__ void k_wcat(const float* __restrict__ Wq, const float* __restrict__ Wv,
                       float* __restrict__ Wc) {
    int idx = blockIdx.x * 256 + threadIdx.x;   // < 256*512
    int k = idx >> 9, c = idx & 511;
    int cc = c & 255;
    int h = cc >> 6, e = cc & 63;
    const float* src = (c < HD) ? Wq : Wv;
    Wc[idx] = src[(h * DIN + k) * 64 + e];
}

// ---------------- K2: GEMM hall = diag(s) X Wc, s computed in-kernel ----------------
// s_row = artanh(clip||x_row||)/clip||x_row||; C row scaling is exactly linear.
__global__ __launch_bounds__(256) void k_gemm(const float* __restrict__ x,
                                              const float* __restrict__ Wc,
                                              float* __restrict__ hall) {
    __shared__ float As[16][68];
    __shared__ float Bs[16][68];
    __shared__ float sld[64];
    int bm = blockIdx.x, bn = blockIdx.y;
    int tid = threadIdx.x;
    int ty = tid >> 4, tx = tid & 15;
    float acc[4][4] = {};
    int rowbase = bm * 64, colbase = bn * 64;
    int am = tid >> 2;
    int ak = (tid & 3) * 4;
    float rsq = 0.f;
    for (int kt = 0; kt < DIN; kt += 16) {
        float4 u = *reinterpret_cast<const float4*>(x + (size_t)(rowbase + am) * DIN + kt + ak);
        rsq = fmaf(u.x, u.x, fmaf(u.y, u.y, fmaf(u.z, u.z, fmaf(u.w, u.w, rsq))));
        As[ak + 0][am] = u.x;
        As[ak + 1][am] = u.y;
        As[ak + 2][am] = u.z;
        As[ak + 3][am] = u.w;
        int bk = tid >> 4, bc = (tid & 15) * 4;
        float4 w4 = *reinterpret_cast<const float4*>(Wc + (size_t)(kt + bk) * COLS + colbase + bc);
        *reinterpret_cast<float4*>(&Bs[bk][bc]) = w4;
        __syncthreads();
        for (int k = 0; k < 16; k++) {
            float4 a4 = *reinterpret_cast<const float4*>(&As[k][ty * 4]);
            float4 b4 = *reinterpret_cast<const float4*>(&Bs[k][tx * 4]);
            float av[4] = {a4.x, a4.y, a4.z, a4.w};
            float bv[4] = {b4.x, b4.y, b4.z, b4.w};
            for (int i = 0; i < 4; i++)
                for (int j = 0; j < 4; j++) acc[i][j] = fmaf(av[i], bv[j], acc[i][j]);
        }
        __syncthreads();
    }
    // s for row am: reduce rsq over the 4 lanes sharing the row
    rsq += __shfl_xor(rsq, 1);
    rsq += __shfl_xor(rsq, 2);
    if ((tid & 3) == 0) {
        float n = sqrtf(rsq);
        n = fminf(fmaxf(n, EPSF), 1.0f - 1e-5f);
        float at = 0.5f * __logf((1.f + n) / (1.f - n));
        sld[am] = at / n;
    }
    __syncthreads();
    for (int i = 0; i < 4; i++) {
        float sc = sld[ty * 4 + i];
        float4 o = make_float4(acc[i][0] * sc, acc[i][1] * sc, acc[i][2] * sc, acc[i][3] * sc);
        *reinterpret_cast<float4*>(hall + (size_t)(rowbase + ty * 4 + i) * COLS + colbase + tx * 4) = o;
    }
}

// ---------------- K2c: hall -> hallT transpose+convert, FUSED with es/ed dots --------
__global__ __launch_bounds__(256) void k_hT(const float* __restrict__ hall,
        const float* __restrict__ aqs, const float* __restrict__ aqd,
        const float* __restrict__ avs, const float* __restrict__ avd,
        unsigned short* __restrict__ hallT, float* __restrict__ esq,
        float* __restrict__ edq, float* __restrict__ esv, float* __restrict__ edv) {
    int jt = blockIdx.x, h = blockIdx.y, b = blockIdx.z;   // 16,4,8
    __shared__ float T[64][69];
    int t = threadIdx.x;
    int bh = b * H + h;
    int jl = t >> 2, cg = t & 3;         // load + dot: row jl, col-chunk cg*16
    int el = t >> 2, seg = t & 3;        // store: e-row el, j-chunk seg*16
    #pragma unroll
    for (int pass = 0; pass < 2; pass++) {
        int colbase = (pass == 0) ? h * 64 : 256 + h * 64;
        const float* as = (pass == 0) ? aqs : avs;
        const float* ad = (pass == 0) ? aqd : avd;
        float* es = (pass == 0) ? esq : esv;
        float* ed = (pass == 0) ? edq : edv;
        __syncthreads();                 // WAR vs previous pass
        {
            const float* src = hall + (size_t)(b * N + jt * 64 + jl) * COLS + colbase + cg * 16;
            #pragma unroll
            for (int u = 0; u < 4; u++) {
                float4 v = *reinterpret_cast<const float4*>(src + u * 4);
                T[jl][cg * 16 + u * 4 + 0] = v.x;
                T[jl][cg * 16 + u * 4 + 1] = v.y;
                T[jl][cg * 16 + u * 4 + 2] = v.z;
                T[jl][cg * 16 + u * 4 + 3] = v.w;
            }
        }
        __syncthreads();
        {   // transposed bf16 store
            unsigned int pk[8];
            #pragma unroll
            for (int k = 0; k < 8; k++) {
                float f0 = T[seg * 16 + 2 * k][el];
                float f1 = T[seg * 16 + 2 * k + 1][el];
                pk[k] = (unsigned)f2bf(f0) | ((unsigned)f2bf(f1) << 16);
            }
            unsigned short* dst = hallT + ((size_t)(bh * 128 + pass * 64 + el)) * 1024
                                  + jt * 64 + seg * 16;
            *reinterpret_cast<uint4*>(dst)     = make_uint4(pk[0], pk[1], pk[2], pk[3]);
            *reinterpret_cast<uint4*>(dst + 8) = make_uint4(pk[4], pk[5], pk[6], pk[7]);
        }
        {   // es/ed dots: 4 lanes per row, 16 elems each, 2-step shfl reduce
            float p1 = 0.f, p2 = 0.f;
            #pragma unroll
            for (int u = 0; u < 16; u++) {
                float hv = T[jl][cg * 16 + u];
                p1 = fmaf(hv, as[h * 64 + cg * 16 + u], p1);
                p2 = fmaf(hv, ad[h * 64 + cg * 16 + u], p2);
            }
            p1 += __shfl_xor(p1, 1); p2 += __shfl_xor(p2, 1);
            p1 += __shfl_xor(p1, 2); p2 += __shfl_xor(p2, 2);
            if (cg == 0) {
                es[(size_t)bh * N + jt * 64 + jl] = p1;
                ed[(size_t)bh * N + jt * 64 + jl] = p2;
            }
        }
    }
}

// ---------------- K3a: softmax stats, h-merged (adj read ONCE per (b,i)) ----------
__global__ void k_stats(const float* __restrict__ adj, const float* __restrict__ esq,
                        const float* __restrict__ edq, const float* __restrict__ esv,
                        const float* __restrict__ edv, float* __restrict__ stats,
                        unsigned char* __restrict__ amask) {
    int pid = blockIdx.x;                 // b*N + i
    int b = pid >> 10, i = pid & 1023;
    int t = threadIdx.x;                  // 128 threads, 8 j each
    const float* arow = adj + (size_t)pid * N + t * 8;
    float4 a0 = *reinterpret_cast<const float4*>(arow);
    float4 a1 = *reinterpret_cast<const float4*>(arow + 4);
    float am[8] = {a0.x, a0.y, a0.z, a0.w, a1.x, a1.y, a1.z, a1.w};
    unsigned mb = 0;
    #pragma unroll
    for (int j = 0; j < 8; j++) mb |= (unsigned)(am[j] > 0.f) << j;
    amask[(size_t)pid * 128 + t] = (unsigned char)mb;

    __shared__ float red[2][2];
    __shared__ float red2[2][2];
    int w = t >> 6;
    for (int h = 0; h < H; h++) {
        int bh = b * H + h;
        float esqi = esq[(size_t)bh * N + i], esvi = esv[(size_t)bh * N + i];
        const float* edqr = edq + (size_t)bh * N + t * 8;
        const float* edvr = edv + (size_t)bh * N + t * 8;
        float4 q0 = *reinterpret_cast<const float4*>(edqr);
        float4 q1 = *reinterpret_cast<const float4*>(edqr + 4);
        float4 w0 = *reinterpret_cast<const float4*>(edvr);
        float4 w1 = *reinterpret_cast<const float4*>(edvr + 4);
        float edqv[8] = {q0.x, q0.y, q0.z, q0.w, q1.x, q1.y, q1.z, q1.w};
        float edvv[8] = {w0.x, w0.y, w0.z, w0.w, w1.x, w1.y, w1.z, w1.w};
        float eq[8], ev[8];
        float mq = -1e30f, mv = -1e30f;
        #pragma unroll
        for (int j = 0; j < 8; j++) {
            bool msk = (mb >> j) & 1;
            float q = esqi + edqv[j]; q = fmaxf(q, 0.2f * q);
            float v = esvi + edvv[j]; v = fmaxf(v, 0.2f * v);
            eq[j] = msk ? q : -1e30f;
            ev[j] = msk ? v : -1e30f;
            mq = fmaxf(mq, eq[j]); mv = fmaxf(mv, ev[j]);
        }
        for (int m = 32; m; m >>= 1) { mq = fmaxf(mq, __shfl_xor(mq, m)); mv = fmaxf(mv, __shfl_xor(mv, m)); }
        if ((t & 63) == 0) { red[w][0] = mq; red[w][1] = mv; }
        __syncthreads();
        mq = fmaxf(red[0][0], red[1][0]);
        mv = fmaxf(red[0][1], red[1][1]);
        float sq_ = 0.f, sv_ = 0.f;
        #pragma unroll
        for (int j = 0; j < 8; j++) { sq_ += __expf(eq[j] - mq); sv_ += __expf(ev[j] - mv); }
        for (int m = 32; m; m >>= 1) { sq_ += __shfl_xor(sq_, m); sv_ += __shfl_xor(sv_, m); }
        if ((t & 63) == 0) { red2[w][0] = sq_; red2[w][1] = sv_; }
        __syncthreads();
        if (t == 0) {
            int bid = bh * N + i;
            stats[bid] = mq;
            stats[BHN + bid] = red2[0][0] + red2[1][0];
            stats[2 * BHN + bid] = mv;
            stats[3 * BHN + bid] = red2[0][1] + red2[1][1];
        }
        __syncthreads();                  // WAR: red/red2 reused next h
    }
}

// ---------------- K3b: MFMA GAT aggregation; exp2-folded weights; unroll-2 MLP ------
__global__ __launch_bounds__(512) void k_aggr(const unsigned char* __restrict__ amask,
        const unsigned short* __restrict__ hallT, const float* __restrict__ esq,
        const float* __restrict__ edq, const float* __restrict__ esv,
        const float* __restrict__ edv, const float* __restrict__ stats,
        float* __restrict__ outq, float* __restrict__ outv) {
    int f = blockIdx.x;
    int g = ((f & 7) << 7) | (f >> 3);        // bijective: 1024 = 8 x 128
    int b = g >> 7;
    int it = (g >> 2) & 31;
    int h = g & 3;
    int bh = b * H + h;
    int i0 = it * 32;
    int t = threadIdx.x;
    int lane = t & 63, wv = t >> 6;           // 0..7
    int team = wv >> 1;                       // j-quarter 0..3
    int mh = wv & 1;                          // i-half

    int i = i0 + mh * 16 + (lane & 15);
    int bi = bh * N + i;
    constexpr float L2E = 1.44269504f;
    float esq_i = esq[bi], esv_i = esv[bi];
    float cq2 = -fmaf(stats[bi],           L2E, __builtin_amdgcn_logf(stats[BHN + bi]));
    float cv2 = -fmaf(stats[2 * BHN + bi], L2E, __builtin_amdgcn_logf(stats[3 * BHN + bi]));
    const unsigned char* mrow = amask + (size_t)(b * N + i) * 128;
    const float* edqrow = edq + (size_t)bh * N;
    const float* edvrow = edv + (size_t)bh * N;
    int klo = lane >> 4;
    const unsigned short* bbq = hallT
        + ((size_t)(bh * 128 + (lane & 15))) * 1024 + klo * 8;
    const unsigned short* bbv = bbq + (size_t)64 * 1024;

    f32x4 accq[4] = {}, accv[4] = {};
    int jbase = team * 256;
    #pragma unroll 2
    for (int jj = 0; jj < 8; jj++) {
        int j0 = jbase + jj * 32;
        unsigned mword = *reinterpret_cast<const unsigned*>(mrow + (j0 >> 3));
        float4 q0 = *reinterpret_cast<const float4*>(edqrow + j0 + klo * 8);
        float4 q1 = *reinterpret_cast<const float4*>(edqrow + j0 + klo * 8 + 4);
        float4 v0 = *reinterpret_cast<const float4*>(edvrow + j0 + klo * 8);
        float4 v1 = *reinterpret_cast<const float4*>(edvrow + j0 + klo * 8 + 4);
        float eq[8] = {q0.x, q0.y, q0.z, q0.w, q1.x, q1.y, q1.z, q1.w};
        float ev[8] = {v0.x, v0.y, v0.z, v0.w, v1.x, v1.y, v1.z, v1.w};
        union { uint4 u4; short8 s8; } pq_, pv_;
        unsigned* uq = reinterpret_cast<unsigned*>(&pq_.u4);
        unsigned* uv = reinterpret_cast<unsigned*>(&pv_.u4);
        #pragma unroll
        for (int pu = 0; pu < 4; pu++) {
            unsigned wq0, wq1, wv0, wv1;
            {
                int u = pu * 2;
                bool on = (mword >> (klo * 8 + u)) & 1;
                float q = esq_i + eq[u]; q = fmaxf(q, 0.2f * q);
                float v = esv_i + ev[u]; v = fmaxf(v, 0.2f * v);
                wq0 = on ? __float_as_uint(__builtin_amdgcn_exp2f(fmaf(q, L2E, cq2))) : 0u;
                wv0 = on ? __float_as_uint(__builtin_amdgcn_exp2f(fmaf(v, L2E, cv2))) : 0u;
            }
            {
                int u = pu * 2 + 1;
                bool on = (mword >> (klo * 8 + u)) & 1;
                float q = esq_i + eq[u]; q = fmaxf(q, 0.2f * q);
                float v = esv_i + ev[u]; v = fmaxf(v, 0.2f * v);
                wq1 = on ? __float_as_uint(__builtin_amdgcn_exp2f(fmaf(q, L2E, cq2))) : 0u;
                wv1 = on ? __float_as_uint(__builtin_amdgcn_exp2f(fmaf(v, L2E, cv2))) : 0u;
            }
            uq[pu] = (wq0 >> 16) | (wq1 & 0xFFFF0000u);   // trunc bf16 pair
            uv[pu] = (wv0 >> 16) | (wv1 & 0xFFFF0000u);
        }
        short8 afq = pq_.s8, afv = pv_.s8;
        #pragma unroll
        for (int nt = 0; nt < 4; nt++) {
            short8 bq = *reinterpret_cast<const short8*>(bbq + j0 + nt * 16384);
            accq[nt] = __builtin_amdgcn_mfma_f32_16x16x32_bf16(afq, bq, accq[nt], 0, 0, 0);
            short8 bv = *reinterpret_cast<const short8*>(bbv + j0 + nt * 16384);
            accv[nt] = __builtin_amdgcn_mfma_f32_16x16x32_bf16(afv, bv, accv[nt], 0, 0, 0);
        }
    }

    // 2-stage team combine: slots = (team>>1)*2 + mh, 4 x 8KB = 32KB
    __shared__ __align__(16) float red[8192];
    int slot = (team >> 1) * 2 + mh;
    float* buf = red + slot * 2048;
    __syncthreads();
    if (team & 1) {                           // teams 1,3 write
        #pragma unroll
        for (int k = 0; k < 4; k++) {
            *reinterpret_cast<f32x4*>(&buf[(k * 64 + lane) * 4])       = accq[k];
            *reinterpret_cast<f32x4*>(&buf[((k + 4) * 64 + lane) * 4]) = accv[k];
        }
    }
    __syncthreads();
    if (!(team & 1)) {                        // teams 0,2 add partner
        #pragma unroll
        for (int k = 0; k < 4; k++) {
            f32x4 pq = *reinterpret_cast<const f32x4*>(&buf[(k * 64 + lane) * 4]);
            f32x4 pv = *reinterpret_cast<const f32x4*>(&buf[((k + 4) * 64 + lane) * 4]);
            accq[k] += pq; accv[k] += pv;
        }
    }
    __syncthreads();
    if (team == 2) {                          // team 2 writes to slots 0,1
        float* d2 = red + mh * 2048;
        #pragma unroll
        for (int k = 0; k < 4; k++) {
            *reinterpret_cast<f32x4*>(&d2[(k * 64 + lane) * 4])       = accq[k];
            *reinterpret_cast<f32x4*>(&d2[((k + 4) * 64 + lane) * 4]) = accv[k];
        }
    }
    __syncthreads();
    if (team == 0) {
        float* s2 = red + mh * 2048;
        #pragma unroll
        for (int nt = 0; nt < 4; nt++) {
            f32x4 pq = *reinterpret_cast<const f32x4*>(&s2[(nt * 64 + lane) * 4]);
            f32x4 pv = *reinterpret_cast<const f32x4*>(&s2[((nt + 4) * 64 + lane) * 4]);
            #pragma unroll
            for (int r = 0; r < 4; r++) {
                int irow = i0 + mh * 16 + (lane >> 4) * 4 + r;
                int e = nt * 16 + (lane & 15);
                outq[(size_t)(b * N + irow) * 256 + h * 64 + e] = accq[nt][r] + pq[r];
                outv[(size_t)(b * N + irow) * 256 + h * 64 + e] = accv[nt][r] + pv[r];
            }
        }
    }
}

// ---------------- K4: expmap0; emits qh/ql (bf16 hi/lo), sq, isr, val ----------------
__global__ void k_expmap(const float* __restrict__ outq, const float* __restrict__ outv,
                         unsigned short* __restrict__ qh, unsigned short* __restrict__ ql,
                         float* __restrict__ sq, float* __restrict__ isr,
                         float* __restrict__ val) {
    int p = blockIdx.x, t = threadIdx.x;
    int h = t >> 6, e = t & 63;
    float v = outq[(size_t)p * HD + t];
    float ss = v * v;
    for (int m = 32; m; m >>= 1) ss += __shfl_xor(ss, m);
    float n = fmaxf(sqrtf(ss), EPSF);
    float tn = tanhf(n);
    float qv = v * (tn / n);
    short hs, ls; tsplit(qv, hs, ls);
    qh[((size_t)p << 8) + t] = (unsigned short)hs;
    ql[((size_t)p << 8) + t] = (unsigned short)ls;
    if (e == 0) {
        float s = tn * tn;
        sq[h * BN + p] = s;
        isr[h * BN + p] = __builtin_amdgcn_rcpf(1.f - s);
    }

    float vv = outv[(size_t)p * HDV + t];
    float s2 = vv * vv;
    for (int m = 32; m; m >>= 1) s2 += __shfl_xor(s2, m);
    __shared__ float part[4];
    if (e == 0) part[h] = s2;
    __syncthreads();
    float tot = part[0] + part[1] + part[2] + part[3];
    float nv = fmaxf(sqrtf(tot), EPSF);
    float sclv = tanhf(nv) / nv;
    val[(size_t)p * HDV + t] = vv * sclv;
}

// ---------------- K5: MFMA pair-dist, barrier-free; B-side hi-only (2 MFMA) --------
// reshape(-1,B,N,N) closed form: h=m2%4, m=(n2%4)*256+m2/4, n=(b2*256+n2/4)%1024, b=2a+b2/4
__global__ __launch_bounds__(256) void k_att(const unsigned short* __restrict__ qh,
        const unsigned short* __restrict__ ql, const float* __restrict__ sq,
        const float* __restrict__ isr, const float* __restrict__ rr,
        const float* __restrict__ tt, float* __restrict__ m_out) {
    int f = blockIdx.x;
    int g = ((f & 7) << 7) | (f >> 3);        // bijective 1024
    int b2 = g >> 7;
    int rem = g & 127;
    int c = rem >> 5, h = (rem >> 3) & 3, kc = (rem >> 1) & 3, xh = rem & 1;
    int t = threadIdx.x;
    int l = t & 63, w = t >> 6;
    int klo = l >> 4;

    int nstart = (b2 * 256 + kc * 64) & 1023;
    int mstart = c * 256 + xh * 128;

    float tacc[8][4] = {};

    #pragma unroll
    for (int a = 0; a < 4; a++) {
        int b = 2 * a + (b2 >> 2);
        size_t xbase = ((size_t)(b * N + nstart + w * 16 + (l & 15)) << 8) + h * 64 + klo * 8;
        short8 Ah[2], Al[2];
        #pragma unroll
        for (int kk = 0; kk < 2; kk++) {
            Ah[kk] = *reinterpret_cast<const short8*>(qh + xbase + kk * 32);
            Al[kk] = *reinterpret_cast<const short8*>(ql + xbase + kk * 32);
        }
        float ra = rr[a], ta = tt[a];
        float c1 = 2.f * ta;                       // ln2*log2e == 1
        float c0 = c1 * ra * 1.44269504f;          // 2*r*t*log2e
        float sxr[4], ixr[4];
        #pragma unroll
        for (int r = 0; r < 4; r++) {
            int gx = h * BN + b * N + nstart + w * 16 + (l >> 4) * 4 + r;
            sxr[r] = sq[gx];
            ixr[r] = 2.f * isr[gx];
        }
        size_t ybase = ((size_t)(b * N + mstart + (l & 15)) << 8) + h * 64 + klo * 8;
        #pragma unroll
        for (int nt = 0; nt < 8; nt++) {
            size_t yb = ybase + ((size_t)(nt * 16) << 8);
            f32x4 acc = {};
            #pragma unroll
            for (int kk = 0; kk < 2; kk++) {
                short8 Bh = *reinterpret_cast<const short8*>(qh + yb + kk * 32);
                acc = __builtin_amdgcn_mfma_f32_16x16x32_bf16(Ah[kk], Bh, acc, 0, 0, 0);
                acc = __builtin_amdgcn_mfma_f32_16x16x32_bf16(Al[kk], Bh, acc, 0, 0, 0);
            }
            int gy = h * BN + b * N + mstart + nt * 16 + (l & 15);
            float sy = sq[gy];
            float iy = isr[gy];
            #pragma unroll
            for (int r = 0; r < 4; r++) {
                float diff = fmaxf(fmaf(-2.f, acc[r], sxr[r] + sy), 0.f);
                float ixy = fminf(ixr[r] * iy, 2e7f);          // 2/max(den,1e-7)
                float z = fmaxf(fmaf(diff, ixy, 1.f), 1.f + EPSF);
                float s_ = z + __builtin_amdgcn_sqrtf(fmaf(z, z, -1.f));   // e^dist
                float l2 = __builtin_amdgcn_logf(s_);                      // log2
                float ex = __builtin_amdgcn_exp2f(fmaf(-c1, l2, c0));      // e^{2u}
                float rc = __builtin_amdgcn_rcpf(ex + 1.f);
                tacc[nt][r] += fmaf(-2.f, rc, 1.f);            // tanh(u), NaN-safe
            }
        }
    }
    // write-out (scrambled reshape positions)
    #pragma unroll
    for (int nt = 0; nt < 8; nt++) {
        #pragma unroll
        for (int r = 0; r < 4; r++) {
            int n_local = w * 16 + (l >> 4) * 4 + r;
            int n2 = c + 4 * (kc * 64 + n_local);
            int mloc = xh * 128 + nt * 16 + (l & 15);
            int m2 = 4 * mloc + h;
            m_out[((size_t)b2 << 20) + ((size_t)n2 << 10) + m2] = 0.25f * tacc[nt][r];
        }
    }
}

// ---------------- K6: in-place symmetrize on d_out att region ----------------
__global__ void k_sym(float* __restrict__ m) {
    int ti = blockIdx.x, tj = blockIdx.y, b = blockIdx.z;
    if (ti > tj) return;
    __shared__ float A[32][33], Bt[32][33];
    int t = threadIdx.x;
    int r = t >> 3, c4 = (t & 7) * 4;
    size_t baseA = ((size_t)b << 20) + (size_t)(ti * 32) * N + tj * 32;
    size_t baseB = ((size_t)b << 20) + (size_t)(tj * 32) * N + ti * 32;
    float4 ua = *reinterpret_cast<const float4*>(m + baseA + (size_t)r * N + c4);
    float4 ub = *reinterpret_cast<const float4*>(m + baseB + (size_t)r * N + c4);
    A[r][c4 + 0] = ua.x; A[r][c4 + 1] = ua.y; A[r][c4 + 2] = ua.z; A[r][c4 + 3] = ua.w;
    Bt[r][c4 + 0] = ub.x; Bt[r][c4 + 1] = ub.y; Bt[r][c4 + 2] = ub.z; Bt[r][c4 + 3] = ub.w;
    __syncthreads();
    for (int u = 0; u < 4; u++) {
        int cc = c4 + u;
        float oa = 0.5f * (A[r][cc] + Bt[cc][r]);
        float ob = 0.5f * (Bt[r][cc] + A[cc][r]);
        m[baseA + (size_t)r * N + cc] = oa;
        m[baseB + (size_t)r * N + cc] = ob;
    }
}

extern "C" void kernel_launch(void* const* d_in, const int* in_sizes, int n_in,
                              void* d_out, int out_size, void* d_ws, size_t ws_size,
                              hipStream_t stream) {
    const float* x   = (const float*)d_in[0];
    const float* adj = (const float*)d_in[1];
    const float* Wq  = (const float*)d_in[3];
    const float* aqs = (const float*)d_in[4];
    const float* aqd = (const float*)d_in[5];
    const float* Wv  = (const float*)d_in[6];
    const float* avs = (const float*)d_in[7];
    const float* avd = (const float*)d_in[8];
    const float* rr  = (const float*)d_in[9];
    const float* tt  = (const float*)d_in[10];

    float* ws = (float*)d_ws;
    float* s     = ws;                            // 8192 (unused slot, kept for layout)
    float* Wc    = s + BN;                        // 131072 f32
    float* hall  = Wc + 256 * COLS;               // 4194304 f32 (16 MB)
    float* esq   = hall + (size_t)BN * COLS;      // 32768 x4
    float* edq   = esq + BHN;
    float* esv   = edq + BHN;
    float* edv   = esv + BHN;
    float* stats = edv + BHN;                     // 4*BHN
    float* outq  = stats + 4 * BHN;               // 2097152
    float* outv  = outq + (size_t)BN * HD;        // 2097152
    float* sq    = outv + (size_t)BN * HDV;       // 32768
    unsigned short* hallT = (unsigned short*)(sq + H * BN);   // BN*COLS bf16 = 8 MB
    unsigned char* amask = (unsigned char*)(hallT + (size_t)BN * COLS); // 1 MB
    size_t need = (size_t)((char*)(amask + (size_t)BN * 128) - (char*)ws);
    if (ws_size < need) return;                   // ws too small: bail visibly

    // qh/ql/isr alias the hall region (dead after k_hT reads it; k_expmap runs later)
    unsigned short* qh = (unsigned short*)hall;
    unsigned short* ql = qh + (size_t)BN * 256;
    float* isr = (float*)(ql + (size_t)BN * 256);

    float* val  = (float*)d_out;
    float* matt = (float*)d_out + (size_t)BN * HDV;

    k_wcat<<<(256 * COLS) / 256, 256, 0, stream>>>(Wq, Wv, Wc);
    k_gemm<<<dim3(BN / 64, COLS / 64), 256, 0, stream>>>(x, Wc, hall);
    k_hT<<<dim3(16, H, B), 256, 0, stream>>>(hall, aqs, aqd, avs, avd,
                                             hallT, esq, edq, esv, edv);
    k_stats<<<BN, 128, 0, stream>>>(adj, esq, edq, esv, edv, stats, amask);
    k_aggr<<<1024, 512, 0, stream>>>(amask, hallT, esq, edq, esv, edv, stats, outq, outv);
    k_expmap<<<BN, 256, 0, stream>>>(outq, outv, qh, ql, sq, isr, val);
    k_att<<<1024, 256, 0, stream>>>(qh, ql, sq, isr, rr, tt, matt);
    k_sym<<<dim3(32, 32, 8), 256, 0, stream>>>(matt);
}

// Round 21
// 218.788 us; speedup vs baseline: 1.0304x; 1.0060x over previous
//
#include <hip/hip_runtime.h>
#include <hip/hip_bf16.h>
#include <math.h>

#define DEV __device__ __forceinline__

constexpr int B = 8, N = 1024, DIN = 256, H = 4, DATT = 64, DV = 64;
constexpr int BN = B * N;             // 8192
constexpr int HD = H * DATT;          // 256
constexpr int HDV = H * DV;           // 256
constexpr int COLS = HD + HDV;        // 512
constexpr int BHN = B * H * N;        // 32768
constexpr float EPSF = 1e-7f;

using short8 = __attribute__((ext_vector_type(8))) short;
using f32x4  = __attribute__((ext_vector_type(4))) float;

DEV unsigned short f2bf(float f) {
    __hip_bfloat16 h = __float2bfloat16(f);
    return *reinterpret_cast<unsigned short*>(&h);
}
DEV float bfu2f(unsigned short u) { return __uint_as_float(((unsigned)u) << 16); }

// truncation hi/lo split: hi=trunc16(v) (exact residual), lo=trunc16(v-hi)
DEV void tsplit(float v, short& hs, short& ls) {
    unsigned vu = __float_as_uint(v);
    float lo = v - __uint_as_float(vu & 0xFFFF0000u);
    hs = (short)(unsigned short)(vu >> 16);
    ls = (short)(unsigned short)(__float_as_uint(lo) >> 16);
}

// ---------------- K0: build Wcat [256][512] f32 (Wq | Wv) ----------------
__global__ void k_wcat(const float* __restrict__ Wq, const float* __restrict__ Wv,
                       float* __restrict__ Wc) {
    int idx = blockIdx.x * 256 + threadIdx.x;   // < 256*512
    int k = idx >> 9, c = idx & 511;
    int cc = c & 255;
    int h = cc >> 6, e = cc & 63;
    const float* src = (c < HD) ? Wq : Wv;
    Wc[idx] = src[(h * DIN + k) * 64 + e];
}

// ---------------- K2: GEMM hall = diag(s) X Wc, s computed in-kernel ----------------
__global__ __launch_bounds__(256) void k_gemm(const float* __restrict__ x,
                                              const float* __restrict__ Wc,
                                              float* __restrict__ hall) {
    __shared__ float As[16][68];
    __shared__ float Bs[16][68];
    __shared__ float sld[64];
    int bm = blockIdx.x, bn = blockIdx.y;
    int tid = threadIdx.x;
    int ty = tid >> 4, tx = tid & 15;
    float acc[4][4] = {};
    int rowbase = bm * 64, colbase = bn * 64;
    int am = tid >> 2;
    int ak = (tid & 3) * 4;
    float rsq = 0.f;
    for (int kt = 0; kt < DIN; kt += 16) {
        float4 u = *reinterpret_cast<const float4*>(x + (size_t)(rowbase + am) * DIN + kt + ak);
        rsq = fmaf(u.x, u.x, fmaf(u.y, u.y, fmaf(u.z, u.z, fmaf(u.w, u.w, rsq))));
        As[ak + 0][am] = u.x;
        As[ak + 1][am] = u.y;
        As[ak + 2][am] = u.z;
        As[ak + 3][am] = u.w;
        int bk = tid >> 4, bc = (tid & 15) * 4;
        float4 w4 = *reinterpret_cast<const float4*>(Wc + (size_t)(kt + bk) * COLS + colbase + bc);
        *reinterpret_cast<float4*>(&Bs[bk][bc]) = w4;
        __syncthreads();
        for (int k = 0; k < 16; k++) {
            float4 a4 = *reinterpret_cast<const float4*>(&As[k][ty * 4]);
            float4 b4 = *reinterpret_cast<const float4*>(&Bs[k][tx * 4]);
            float av[4] = {a4.x, a4.y, a4.z, a4.w};
            float bv[4] = {b4.x, b4.y, b4.z, b4.w};
            for (int i = 0; i < 4; i++)
                for (int j = 0; j < 4; j++) acc[i][j] = fmaf(av[i], bv[j], acc[i][j]);
        }
        __syncthreads();
    }
    rsq += __shfl_xor(rsq, 1);
    rsq += __shfl_xor(rsq, 2);
    if ((tid & 3) == 0) {
        float n = sqrtf(rsq);
        n = fminf(fmaxf(n, EPSF), 1.0f - 1e-5f);
        float at = 0.5f * __logf((1.f + n) / (1.f - n));
        sld[am] = at / n;
    }
    __syncthreads();
    for (int i = 0; i < 4; i++) {
        float sc = sld[ty * 4 + i];
        float4 o = make_float4(acc[i][0] * sc, acc[i][1] * sc, acc[i][2] * sc, acc[i][3] * sc);
        *reinterpret_cast<float4*>(hall + (size_t)(rowbase + ty * 4 + i) * COLS + colbase + tx * 4) = o;
    }
}

// ---------------- K2c: hall -> hallT transpose+convert, FUSED with es/ed dots --------
__global__ __launch_bounds__(256) void k_hT(const float* __restrict__ hall,
        const float* __restrict__ aqs, const float* __restrict__ aqd,
        const float* __restrict__ avs, const float* __restrict__ avd,
        unsigned short* __restrict__ hallT, float* __restrict__ esq,
        float* __restrict__ edq, float* __restrict__ esv, float* __restrict__ edv) {
    int jt = blockIdx.x, h = blockIdx.y, b = blockIdx.z;   // 16,4,8
    __shared__ float T[64][69];
    int t = threadIdx.x;
    int bh = b * H + h;
    int jl = t >> 2, cg = t & 3;         // load + dot: row jl, col-chunk cg*16
    int el = t >> 2, seg = t & 3;        // store: e-row el, j-chunk seg*16
    #pragma unroll
    for (int pass = 0; pass < 2; pass++) {
        int colbase = (pass == 0) ? h * 64 : 256 + h * 64;
        const float* as = (pass == 0) ? aqs : avs;
        const float* ad = (pass == 0) ? aqd : avd;
        float* es = (pass == 0) ? esq : esv;
        float* ed = (pass == 0) ? edq : edv;
        __syncthreads();                 // WAR vs previous pass
        {
            const float* src = hall + (size_t)(b * N + jt * 64 + jl) * COLS + colbase + cg * 16;
            #pragma unroll
            for (int u = 0; u < 4; u++) {
                float4 v = *reinterpret_cast<const float4*>(src + u * 4);
                T[jl][cg * 16 + u * 4 + 0] = v.x;
                T[jl][cg * 16 + u * 4 + 1] = v.y;
                T[jl][cg * 16 + u * 4 + 2] = v.z;
                T[jl][cg * 16 + u * 4 + 3] = v.w;
            }
        }
        __syncthreads();
        {   // transposed bf16 store
            unsigned int pk[8];
            #pragma unroll
            for (int k = 0; k < 8; k++) {
                float f0 = T[seg * 16 + 2 * k][el];
                float f1 = T[seg * 16 + 2 * k + 1][el];
                pk[k] = (unsigned)f2bf(f0) | ((unsigned)f2bf(f1) << 16);
            }
            unsigned short* dst = hallT + ((size_t)(bh * 128 + pass * 64 + el)) * 1024
                                  + jt * 64 + seg * 16;
            *reinterpret_cast<uint4*>(dst)     = make_uint4(pk[0], pk[1], pk[2], pk[3]);
            *reinterpret_cast<uint4*>(dst + 8) = make_uint4(pk[4], pk[5], pk[6], pk[7]);
        }
        {   // es/ed dots: 4 lanes per row, 16 elems each, 2-step shfl reduce
            float p1 = 0.f, p2 = 0.f;
            #pragma unroll
            for (int u = 0; u < 16; u++) {
                float hv = T[jl][cg * 16 + u];
                p1 = fmaf(hv, as[h * 64 + cg * 16 + u], p1);
                p2 = fmaf(hv, ad[h * 64 + cg * 16 + u], p2);
            }
            p1 += __shfl_xor(p1, 1); p2 += __shfl_xor(p2, 1);
            p1 += __shfl_xor(p1, 2); p2 += __shfl_xor(p2, 2);
            if (cg == 0) {
                es[(size_t)bh * N + jt * 64 + jl] = p1;
                ed[(size_t)bh * N + jt * 64 + jl] = p2;
            }
        }
    }
}

// ---------------- K3a: softmax stats, h-merged (adj read ONCE per (b,i)) ----------
__global__ void k_stats(const float* __restrict__ adj, const float* __restrict__ esq,
                        const float* __restrict__ edq, const float* __restrict__ esv,
                        const float* __restrict__ edv, float* __restrict__ stats,
                        unsigned char* __restrict__ amask) {
    int pid = blockIdx.x;                 // b*N + i
    int b = pid >> 10, i = pid & 1023;
    int t = threadIdx.x;                  // 128 threads, 8 j each
    const float* arow = adj + (size_t)pid * N + t * 8;
    float4 a0 = *reinterpret_cast<const float4*>(arow);
    float4 a1 = *reinterpret_cast<const float4*>(arow + 4);
    float am[8] = {a0.x, a0.y, a0.z, a0.w, a1.x, a1.y, a1.z, a1.w};
    unsigned mb = 0;
    #pragma unroll
    for (int j = 0; j < 8; j++) mb |= (unsigned)(am[j] > 0.f) << j;
    amask[(size_t)pid * 128 + t] = (unsigned char)mb;

    __shared__ float red[2][2];
    __shared__ float red2[2][2];
    int w = t >> 6;
    for (int h = 0; h < H; h++) {
        int bh = b * H + h;
        float esqi = esq[(size_t)bh * N + i], esvi = esv[(size_t)bh * N + i];
        const float* edqr = edq + (size_t)bh * N + t * 8;
        const float* edvr = edv + (size_t)bh * N + t * 8;
        float4 q0 = *reinterpret_cast<const float4*>(edqr);
        float4 q1 = *reinterpret_cast<const float4*>(edqr + 4);
        float4 w0 = *reinterpret_cast<const float4*>(edvr);
        float4 w1 = *reinterpret_cast<const float4*>(edvr + 4);
        float edqv[8] = {q0.x, q0.y, q0.z, q0.w, q1.x, q1.y, q1.z, q1.w};
        float edvv[8] = {w0.x, w0.y, w0.z, w0.w, w1.x, w1.y, w1.z, w1.w};
        float eq[8], ev[8];
        float mq = -1e30f, mv = -1e30f;
        #pragma unroll
        for (int j = 0; j < 8; j++) {
            bool msk = (mb >> j) & 1;
            float q = esqi + edqv[j]; q = fmaxf(q, 0.2f * q);
            float v = esvi + edvv[j]; v = fmaxf(v, 0.2f * v);
            eq[j] = msk ? q : -1e30f;
            ev[j] = msk ? v : -1e30f;
            mq = fmaxf(mq, eq[j]); mv = fmaxf(mv, ev[j]);
        }
        for (int m = 32; m; m >>= 1) { mq = fmaxf(mq, __shfl_xor(mq, m)); mv = fmaxf(mv, __shfl_xor(mv, m)); }
        if ((t & 63) == 0) { red[w][0] = mq; red[w][1] = mv; }
        __syncthreads();
        mq = fmaxf(red[0][0], red[1][0]);
        mv = fmaxf(red[0][1], red[1][1]);
        float sq_ = 0.f, sv_ = 0.f;
        #pragma unroll
        for (int j = 0; j < 8; j++) { sq_ += __expf(eq[j] - mq); sv_ += __expf(ev[j] - mv); }
        for (int m = 32; m; m >>= 1) { sq_ += __shfl_xor(sq_, m); sv_ += __shfl_xor(sv_, m); }
        if ((t & 63) == 0) { red2[w][0] = sq_; red2[w][1] = sv_; }
        __syncthreads();
        if (t == 0) {
            int bid = bh * N + i;
            stats[bid] = mq;
            stats[BHN + bid] = red2[0][0] + red2[1][0];
            stats[2 * BHN + bid] = mv;
            stats[3 * BHN + bid] = red2[0][1] + red2[1][1];
        }
        __syncthreads();                  // WAR: red/red2 reused next h
    }
}

// ---------------- K3b: MFMA GAT aggregation; exp2-folded weights; unroll-4 MLP ------
__global__ __launch_bounds__(512) void k_aggr(const unsigned char* __restrict__ amask,
        const unsigned short* __restrict__ hallT, const float* __restrict__ esq,
        const float* __restrict__ edq, const float* __restrict__ esv,
        const float* __restrict__ edv, const float* __restrict__ stats,
        float* __restrict__ outq, float* __restrict__ outv) {
    int f = blockIdx.x;
    int g = ((f & 7) << 7) | (f >> 3);        // bijective: 1024 = 8 x 128
    int b = g >> 7;
    int it = (g >> 2) & 31;
    int h = g & 3;
    int bh = b * H + h;
    int i0 = it * 32;
    int t = threadIdx.x;
    int lane = t & 63, wv = t >> 6;           // 0..7
    int team = wv >> 1;                       // j-quarter 0..3
    int mh = wv & 1;                          // i-half

    int i = i0 + mh * 16 + (lane & 15);
    int bi = bh * N + i;
    constexpr float L2E = 1.44269504f;
    float esq_i = esq[bi], esv_i = esv[bi];
    float cq2 = -fmaf(stats[bi],           L2E, __builtin_amdgcn_logf(stats[BHN + bi]));
    float cv2 = -fmaf(stats[2 * BHN + bi], L2E, __builtin_amdgcn_logf(stats[3 * BHN + bi]));
    const unsigned char* mrow = amask + (size_t)(b * N + i) * 128;
    const float* edqrow = edq + (size_t)bh * N;
    const float* edvrow = edv + (size_t)bh * N;
    int klo = lane >> 4;
    const unsigned short* bbq = hallT
        + ((size_t)(bh * 128 + (lane & 15))) * 1024 + klo * 8;
    const unsigned short* bbv = bbq + (size_t)64 * 1024;

    f32x4 accq[4] = {}, accv[4] = {};
    int jbase = team * 256;
    #pragma unroll 4
    for (int jj = 0; jj < 8; jj++) {
        int j0 = jbase + jj * 32;
        unsigned mword = *reinterpret_cast<const unsigned*>(mrow + (j0 >> 3));
        float4 q0 = *reinterpret_cast<const float4*>(edqrow + j0 + klo * 8);
        float4 q1 = *reinterpret_cast<const float4*>(edqrow + j0 + klo * 8 + 4);
        float4 v0 = *reinterpret_cast<const float4*>(edvrow + j0 + klo * 8);
        float4 v1 = *reinterpret_cast<const float4*>(edvrow + j0 + klo * 8 + 4);
        float eq[8] = {q0.x, q0.y, q0.z, q0.w, q1.x, q1.y, q1.z, q1.w};
        float ev[8] = {v0.x, v0.y, v0.z, v0.w, v1.x, v1.y, v1.z, v1.w};
        union { uint4 u4; short8 s8; } pq_, pv_;
        unsigned* uq = reinterpret_cast<unsigned*>(&pq_.u4);
        unsigned* uv = reinterpret_cast<unsigned*>(&pv_.u4);
        #pragma unroll
        for (int pu = 0; pu < 4; pu++) {
            unsigned wq0, wq1, wv0, wv1;
            {
                int u = pu * 2;
                bool on = (mword >> (klo * 8 + u)) & 1;
                float q = esq_i + eq[u]; q = fmaxf(q, 0.2f * q);
                float v = esv_i + ev[u]; v = fmaxf(v, 0.2f * v);
                wq0 = on ? __float_as_uint(__builtin_amdgcn_exp2f(fmaf(q, L2E, cq2))) : 0u;
                wv0 = on ? __float_as_uint(__builtin_amdgcn_exp2f(fmaf(v, L2E, cv2))) : 0u;
            }
            {
                int u = pu * 2 + 1;
                bool on = (mword >> (klo * 8 + u)) & 1;
                float q = esq_i + eq[u]; q = fmaxf(q, 0.2f * q);
                float v = esv_i + ev[u]; v = fmaxf(v, 0.2f * v);
                wq1 = on ? __float_as_uint(__builtin_amdgcn_exp2f(fmaf(q, L2E, cq2))) : 0u;
                wv1 = on ? __float_as_uint(__builtin_amdgcn_exp2f(fmaf(v, L2E, cv2))) : 0u;
            }
            uq[pu] = (wq0 >> 16) | (wq1 & 0xFFFF0000u);   // trunc bf16 pair
            uv[pu] = (wv0 >> 16) | (wv1 & 0xFFFF0000u);
        }
        short8 afq = pq_.s8, afv = pv_.s8;
        #pragma unroll
        for (int nt = 0; nt < 4; nt++) {
            short8 bq = *reinterpret_cast<const short8*>(bbq + j0 + nt * 16384);
            accq[nt] = __builtin_amdgcn_mfma_f32_16x16x32_bf16(afq, bq, accq[nt], 0, 0, 0);
            short8 bv = *reinterpret_cast<const short8*>(bbv + j0 + nt * 16384);
            accv[nt] = __builtin_amdgcn_mfma_f32_16x16x32_bf16(afv, bv, accv[nt], 0, 0, 0);
        }
    }

    // 2-stage team combine: slots = (team>>1)*2 + mh, 4 x 8KB = 32KB
    __shared__ __align__(16) float red[8192];
    int slot = (team >> 1) * 2 + mh;
    float* buf = red + slot * 2048;
    __syncthreads();
    if (team & 1) {                           // teams 1,3 write
        #pragma unroll
        for (int k = 0; k < 4; k++) {
            *reinterpret_cast<f32x4*>(&buf[(k * 64 + lane) * 4])       = accq[k];
            *reinterpret_cast<f32x4*>(&buf[((k + 4) * 64 + lane) * 4]) = accv[k];
        }
    }
    __syncthreads();
    if (!(team & 1)) {                        // teams 0,2 add partner
        #pragma unroll
        for (int k = 0; k < 4; k++) {
            f32x4 pq = *reinterpret_cast<const f32x4*>(&buf[(k * 64 + lane) * 4]);
            f32x4 pv = *reinterpret_cast<const f32x4*>(&buf[((k + 4) * 64 + lane) * 4]);
            accq[k] += pq; accv[k] += pv;
        }
    }
    __syncthreads();
    if (team == 2) {                          // team 2 writes to slots 0,1
        float* d2 = red + mh * 2048;
        #pragma unroll
        for (int k = 0; k < 4; k++) {
            *reinterpret_cast<f32x4*>(&d2[(k * 64 + lane) * 4])       = accq[k];
            *reinterpret_cast<f32x4*>(&d2[((k + 4) * 64 + lane) * 4]) = accv[k];
        }
    }
    __syncthreads();
    if (team == 0) {
        float* s2 = red + mh * 2048;
        #pragma unroll
        for (int nt = 0; nt < 4; nt++) {
            f32x4 pq = *reinterpret_cast<const f32x4*>(&s2[(nt * 64 + lane) * 4]);
            f32x4 pv = *reinterpret_cast<const f32x4*>(&s2[((nt + 4) * 64 + lane) * 4]);
            #pragma unroll
            for (int r = 0; r < 4; r++) {
                int irow = i0 + mh * 16 + (lane >> 4) * 4 + r;
                int e = nt * 16 + (lane & 15);
                outq[(size_t)(b * N + irow) * 256 + h * 64 + e] = accq[nt][r] + pq[r];
                outv[(size_t)(b * N + irow) * 256 + h * 64 + e] = accv[nt][r] + pv[r];
            }
        }
    }
}

// ---------------- K4: expmap0; emits qh/ql (bf16 hi/lo), sq, isr, val ----------------
__global__ void k_expmap(const float* __restrict__ outq, const float* __restrict__ outv,
                         unsigned short* __restrict__ qh, unsigned short* __restrict__ ql,
                         float* __restrict__ sq, float* __restrict__ isr,
                         float* __restrict__ val) {
    int p = blockIdx.x, t = threadIdx.x;
    int h = t >> 6, e = t & 63;
    float v = outq[(size_t)p * HD + t];
    float ss = v * v;
    for (int m = 32; m; m >>= 1) ss += __shfl_xor(ss, m);
    float n = fmaxf(sqrtf(ss), EPSF);
    float tn = tanhf(n);
    float qv = v * (tn / n);
    short hs, ls; tsplit(qv, hs, ls);
    qh[((size_t)p << 8) + t] = (unsigned short)hs;
    ql[((size_t)p << 8) + t] = (unsigned short)ls;
    if (e == 0) {
        float s = tn * tn;
        sq[h * BN + p] = s;
        isr[h * BN + p] = __builtin_amdgcn_rcpf(1.f - s);
    }

    float vv = outv[(size_t)p * HDV + t];
    float s2 = vv * vv;
    for (int m = 32; m; m >>= 1) s2 += __shfl_xor(s2, m);
    __shared__ float part[4];
    if (e == 0) part[h] = s2;
    __syncthreads();
    float tot = part[0] + part[1] + part[2] + part[3];
    float nv = fmaxf(sqrtf(tot), EPSF);
    float sclv = tanhf(nv) / nv;
    val[(size_t)p * HDV + t] = vv * sclv;
}

// ---------------- K5: MFMA pair-dist, barrier-free; B-side hi-only (2 MFMA) --------
// reshape(-1,B,N,N) closed form: h=m2%4, m=(n2%4)*256+m2/4, n=(b2*256+n2/4)%1024, b=2a+b2/4
__global__ __launch_bounds__(256) void k_att(const unsigned short* __restrict__ qh,
        const unsigned short* __restrict__ ql, const float* __restrict__ sq,
        const float* __restrict__ isr, const float* __restrict__ rr,
        const float* __restrict__ tt, float* __restrict__ m_out) {
    int f = blockIdx.x;
    int g = ((f & 7) << 7) | (f >> 3);        // bijective 1024
    int b2 = g >> 7;
    int rem = g & 127;
    int c = rem >> 5, h = (rem >> 3) & 3, kc = (rem >> 1) & 3, xh = rem & 1;
    int t = threadIdx.x;
    int l = t & 63, w = t >> 6;
    int klo = l >> 4;

    int nstart = (b2 * 256 + kc * 64) & 1023;
    int mstart = c * 256 + xh * 128;

    float tacc[8][4] = {};

    #pragma unroll
    for (int a = 0; a < 4; a++) {
        int b = 2 * a + (b2 >> 2);
        size_t xbase = ((size_t)(b * N + nstart + w * 16 + (l & 15)) << 8) + h * 64 + klo * 8;
        short8 Ah[2], Al[2];
        #pragma unroll
        for (int kk = 0; kk < 2; kk++) {
            Ah[kk] = *reinterpret_cast<const short8*>(qh + xbase + kk * 32);
            Al[kk] = *reinterpret_cast<const short8*>(ql + xbase + kk * 32);
        }
        float ra = rr[a], ta = tt[a];
        float c1 = 2.f * ta;                       // ln2*log2e == 1
        float c0 = c1 * ra * 1.44269504f;          // 2*r*t*log2e
        float sxr[4], ixr[4];
        #pragma unroll
        for (int r = 0; r < 4; r++) {
            int gx = h * BN + b * N + nstart + w * 16 + (l >> 4) * 4 + r;
            sxr[r] = sq[gx];
            ixr[r] = 2.f * isr[gx];
        }
        size_t ybase = ((size_t)(b * N + mstart + (l & 15)) << 8) + h * 64 + klo * 8;
        #pragma unroll
        for (int nt = 0; nt < 8; nt++) {
            size_t yb = ybase + ((size_t)(nt * 16) << 8);
            f32x4 acc = {};
            #pragma unroll
            for (int kk = 0; kk < 2; kk++) {
                short8 Bh = *reinterpret_cast<const short8*>(qh + yb + kk * 32);
                acc = __builtin_amdgcn_mfma_f32_16x16x32_bf16(Ah[kk], Bh, acc, 0, 0, 0);
                acc = __builtin_amdgcn_mfma_f32_16x16x32_bf16(Al[kk], Bh, acc, 0, 0, 0);
            }
            int gy = h * BN + b * N + mstart + nt * 16 + (l & 15);
            float sy = sq[gy];
            float iy = isr[gy];
            #pragma unroll
            for (int r = 0; r < 4; r++) {
                float diff = fmaxf(fmaf(-2.f, acc[r], sxr[r] + sy), 0.f);
                float ixy = fminf(ixr[r] * iy, 2e7f);          // 2/max(den,1e-7)
                float z = fmaxf(fmaf(diff, ixy, 1.f), 1.f + EPSF);
                float s_ = z + __builtin_amdgcn_sqrtf(fmaf(z, z, -1.f));   // e^dist
                float l2 = __builtin_amdgcn_logf(s_);                      // log2
                float ex = __builtin_amdgcn_exp2f(fmaf(-c1, l2, c0));      // e^{2u}
                float rc = __builtin_amdgcn_rcpf(ex + 1.f);
                tacc[nt][r] += fmaf(-2.f, rc, 1.f);            // tanh(u), NaN-safe
            }
        }
    }
    // write-out (scrambled reshape positions)
    #pragma unroll
    for (int nt = 0; nt < 8; nt++) {
        #pragma unroll
        for (int r = 0; r < 4; r++) {
            int n_local = w * 16 + (l >> 4) * 4 + r;
            int n2 = c + 4 * (kc * 64 + n_local);
            int mloc = xh * 128 + nt * 16 + (l & 15);
            int m2 = 4 * mloc + h;
            m_out[((size_t)b2 << 20) + ((size_t)n2 << 10) + m2] = 0.25f * tacc[nt][r];
        }
    }
}

// ---------------- K6: in-place symmetrize on d_out att region ----------------
__global__ void k_sym(float* __restrict__ m) {
    int ti = blockIdx.x, tj = blockIdx.y, b = blockIdx.z;
    if (ti > tj) return;
    __shared__ float A[32][33], Bt[32][33];
    int t = threadIdx.x;
    int r = t >> 3, c4 = (t & 7) * 4;
    size_t baseA = ((size_t)b << 20) + (size_t)(ti * 32) * N + tj * 32;
    size_t baseB = ((size_t)b << 20) + (size_t)(tj * 32) * N + ti * 32;
    float4 ua = *reinterpret_cast<const float4*>(m + baseA + (size_t)r * N + c4);
    float4 ub = *reinterpret_cast<const float4*>(m + baseB + (size_t)r * N + c4);
    A[r][c4 + 0] = ua.x; A[r][c4 + 1] = ua.y; A[r][c4 + 2] = ua.z; A[r][c4 + 3] = ua.w;
    Bt[r][c4 + 0] = ub.x; Bt[r][c4 + 1] = ub.y; Bt[r][c4 + 2] = ub.z; Bt[r][c4 + 3] = ub.w;
    __syncthreads();
    for (int u = 0; u < 4; u++) {
        int cc = c4 + u;
        float oa = 0.5f * (A[r][cc] + Bt[cc][r]);
        float ob = 0.5f * (Bt[r][cc] + A[cc][r]);
        m[baseA + (size_t)r * N + cc] = oa;
        m[baseB + (size_t)r * N + cc] = ob;
    }
}

extern "C" void kernel_launch(void* const* d_in, const int* in_sizes, int n_in,
                              void* d_out, int out_size, void* d_ws, size_t ws_size,
                              hipStream_t stream) {
    const float* x   = (const float*)d_in[0];
    const float* adj = (const float*)d_in[1];
    const float* Wq  = (const float*)d_in[3];
    const float* aqs = (const float*)d_in[4];
    const float* aqd = (const float*)d_in[5];
    const float* Wv  = (const float*)d_in[6];
    const float* avs = (const float*)d_in[7];
    const float* avd = (const float*)d_in[8];
    const float* rr  = (const float*)d_in[9];
    const float* tt  = (const float*)d_in[10];

    float* ws = (float*)d_ws;
    float* s     = ws;                            // 8192 (unused slot, kept for layout)
    float* Wc    = s + BN;                        // 131072 f32
    float* hall  = Wc + 256 * COLS;               // 4194304 f32 (16 MB)
    float* esq   = hall + (size_t)BN * COLS;      // 32768 x4
    float* edq   = esq + BHN;
    float* esv   = edq + BHN;
    float* edv   = esv + BHN;
    float* stats = edv + BHN;                     // 4*BHN
    float* outq  = stats + 4 * BHN;               // 2097152
    float* outv  = outq + (size_t)BN * HD;        // 2097152
    float* sq    = outv + (size_t)BN * HDV;       // 32768
    unsigned short* hallT = (unsigned short*)(sq + H * BN);   // BN*COLS bf16 = 8 MB
    unsigned char* amask = (unsigned char*)(hallT + (size_t)BN * COLS); // 1 MB
    size_t need = (size_t)((char*)(amask + (size_t)BN * 128) - (char*)ws);
    if (ws_size < need) return;                   // ws too small: bail visibly

    // qh/ql/isr alias the hall region (dead after k_hT reads it; k_expmap runs later)
    unsigned short* qh = (unsigned short*)hall;
    unsigned short* ql = qh + (size_t)BN * 256;
    float* isr = (float*)(ql + (size_t)BN * 256);

    float* val  = (float*)d_out;
    float* matt = (float*)d_out + (size_t)BN * HDV;

    k_wcat<<<(256 * COLS) / 256, 256, 0, stream>>>(Wq, Wv, Wc);
    k_gemm<<<dim3(BN / 64, COLS / 64), 256, 0, stream>>>(x, Wc, hall);
    k_hT<<<dim3(16, H, B), 256, 0, stream>>>(hall, aqs, aqd, avs, avd,
                                             hallT, esq, edq, esv, edv);
    k_stats<<<BN, 128, 0, stream>>>(adj, esq, edq, esv, edv, stats, amask);
    k_aggr<<<1024, 512, 0, stream>>>(amask, hallT, esq, edq, esv, edv, stats, outq, outv);
    k_expmap<<<BN, 256, 0, stream>>>(outq, outv, qh, ql, sq, isr, val);
    k_att<<<1024, 256, 0, stream>>>(qh, ql, sq, isr, rr, tt, matt);
    k_sym<<<dim3(32, 32, 8), 256, 0, stream>>>(matt);
}

// Round 22
// 217.100 us; speedup vs baseline: 1.0384x; 1.0078x over previous
//
#include <hip/hip_runtime.h>
#include <hip/hip_bf16.h>
#include <math.h>

#define DEV __device__ __forceinline__

constexpr int B = 8, N = 1024, DIN = 256, H = 4, DATT = 64, DV = 64;
constexpr int BN = B * N;             // 8192
constexpr int HD = H * DATT;          // 256
constexpr int HDV = H * DV;           // 256
constexpr int COLS = HD + HDV;        // 512
constexpr int BHN = B * H * N;        // 32768
constexpr float EPSF = 1e-7f;

using short8 = __attribute__((ext_vector_type(8))) short;
using f32x4  = __attribute__((ext_vector_type(4))) float;

DEV unsigned short f2bf(float f) {
    __hip_bfloat16 h = __float2bfloat16(f);
    return *reinterpret_cast<unsigned short*>(&h);
}
DEV float bfu2f(unsigned short u) { return __uint_as_float(((unsigned)u) << 16); }

// truncation hi/lo split: hi=trunc16(v) (exact residual), lo=trunc16(v-hi)
DEV void tsplit(float v, short& hs, short& ls) {
    unsigned vu = __float_as_uint(v);
    float lo = v - __uint_as_float(vu & 0xFFFF0000u);
    hs = (short)(unsigned short)(vu >> 16);
    ls = (short)(unsigned short)(__float_as_uint(lo) >> 16);
}

// ---------------- K0: build Wcat [256][512] f32 (Wq | Wv) ----------------
__global__ void k_wcat(const float* __restrict__ Wq, const float* __restrict__ Wv,
                       float* __restrict__ Wc) {
    int idx = blockIdx.x * 256 + threadIdx.x;   // < 256*512
    int k = idx >> 9, c = idx & 511;
    int cc = c & 255;
    int h = cc >> 6, e = cc & 63;
    const float* src = (c < HD) ? Wq : Wv;
    Wc[idx] = src[(h * DIN + k) * 64 + e];
}

// ---------------- K2: GEMM hall = diag(s) X Wc, s computed in-kernel ----------------
__global__ __launch_bounds__(256) void k_gemm(const float* __restrict__ x,
                                              const float* __restrict__ Wc,
                                              float* __restrict__ hall) {
    __shared__ float As[16][68];
    __shared__ float Bs[16][68];
    __shared__ float sld[64];
    int bm = blockIdx.x, bn = blockIdx.y;
    int tid = threadIdx.x;
    int ty = tid >> 4, tx = tid & 15;
    float acc[4][4] = {};
    int rowbase = bm * 64, colbase = bn * 64;
    int am = tid >> 2;
    int ak = (tid & 3) * 4;
    float rsq = 0.f;
    for (int kt = 0; kt < DIN; kt += 16) {
        float4 u = *reinterpret_cast<const float4*>(x + (size_t)(rowbase + am) * DIN + kt + ak);
        rsq = fmaf(u.x, u.x, fmaf(u.y, u.y, fmaf(u.z, u.z, fmaf(u.w, u.w, rsq))));
        As[ak + 0][am] = u.x;
        As[ak + 1][am] = u.y;
        As[ak + 2][am] = u.z;
        As[ak + 3][am] = u.w;
        int bk = tid >> 4, bc = (tid & 15) * 4;
        float4 w4 = *reinterpret_cast<const float4*>(Wc + (size_t)(kt + bk) * COLS + colbase + bc);
        *reinterpret_cast<float4*>(&Bs[bk][bc]) = w4;
        __syncthreads();
        for (int k = 0; k < 16; k++) {
            float4 a4 = *reinterpret_cast<const float4*>(&As[k][ty * 4]);
            float4 b4 = *reinterpret_cast<const float4*>(&Bs[k][tx * 4]);
            float av[4] = {a4.x, a4.y, a4.z, a4.w};
            float bv[4] = {b4.x, b4.y, b4.z, b4.w};
            for (int i = 0; i < 4; i++)
                for (int j = 0; j < 4; j++) acc[i][j] = fmaf(av[i], bv[j], acc[i][j]);
        }
        __syncthreads();
    }
    rsq += __shfl_xor(rsq, 1);
    rsq += __shfl_xor(rsq, 2);
    if ((tid & 3) == 0) {
        float n = sqrtf(rsq);
        n = fminf(fmaxf(n, EPSF), 1.0f - 1e-5f);
        float at = 0.5f * __logf((1.f + n) / (1.f - n));
        sld[am] = at / n;
    }
    __syncthreads();
    for (int i = 0; i < 4; i++) {
        float sc = sld[ty * 4 + i];
        float4 o = make_float4(acc[i][0] * sc, acc[i][1] * sc, acc[i][2] * sc, acc[i][3] * sc);
        *reinterpret_cast<float4*>(hall + (size_t)(rowbase + ty * 4 + i) * COLS + colbase + tx * 4) = o;
    }
}

// ---------------- K2c: hall -> hallT transpose+convert, FUSED with es/ed dots --------
__global__ __launch_bounds__(256) void k_hT(const float* __restrict__ hall,
        const float* __restrict__ aqs, const float* __restrict__ aqd,
        const float* __restrict__ avs, const float* __restrict__ avd,
        unsigned short* __restrict__ hallT, float* __restrict__ esq,
        float* __restrict__ edq, float* __restrict__ esv, float* __restrict__ edv) {
    int jt = blockIdx.x, h = blockIdx.y, b = blockIdx.z;   // 16,4,8
    __shared__ float T[64][69];
    int t = threadIdx.x;
    int bh = b * H + h;
    int jl = t >> 2, cg = t & 3;         // load + dot: row jl, col-chunk cg*16
    int el = t >> 2, seg = t & 3;        // store: e-row el, j-chunk seg*16
    #pragma unroll
    for (int pass = 0; pass < 2; pass++) {
        int colbase = (pass == 0) ? h * 64 : 256 + h * 64;
        const float* as = (pass == 0) ? aqs : avs;
        const float* ad = (pass == 0) ? aqd : avd;
        float* es = (pass == 0) ? esq : esv;
        float* ed = (pass == 0) ? edq : edv;
        __syncthreads();                 // WAR vs previous pass
        {
            const float* src = hall + (size_t)(b * N + jt * 64 + jl) * COLS + colbase + cg * 16;
            #pragma unroll
            for (int u = 0; u < 4; u++) {
                float4 v = *reinterpret_cast<const float4*>(src + u * 4);
                T[jl][cg * 16 + u * 4 + 0] = v.x;
                T[jl][cg * 16 + u * 4 + 1] = v.y;
                T[jl][cg * 16 + u * 4 + 2] = v.z;
                T[jl][cg * 16 + u * 4 + 3] = v.w;
            }
        }
        __syncthreads();
        {   // transposed bf16 store
            unsigned int pk[8];
            #pragma unroll
            for (int k = 0; k < 8; k++) {
                float f0 = T[seg * 16 + 2 * k][el];
                float f1 = T[seg * 16 + 2 * k + 1][el];
                pk[k] = (unsigned)f2bf(f0) | ((unsigned)f2bf(f1) << 16);
            }
            unsigned short* dst = hallT + ((size_t)(bh * 128 + pass * 64 + el)) * 1024
                                  + jt * 64 + seg * 16;
            *reinterpret_cast<uint4*>(dst)     = make_uint4(pk[0], pk[1], pk[2], pk[3]);
            *reinterpret_cast<uint4*>(dst + 8) = make_uint4(pk[4], pk[5], pk[6], pk[7]);
        }
        {   // es/ed dots: 4 lanes per row, 16 elems each, 2-step shfl reduce
            float p1 = 0.f, p2 = 0.f;
            #pragma unroll
            for (int u = 0; u < 16; u++) {
                float hv = T[jl][cg * 16 + u];
                p1 = fmaf(hv, as[h * 64 + cg * 16 + u], p1);
                p2 = fmaf(hv, ad[h * 64 + cg * 16 + u], p2);
            }
            p1 += __shfl_xor(p1, 1); p2 += __shfl_xor(p2, 1);
            p1 += __shfl_xor(p1, 2); p2 += __shfl_xor(p2, 2);
            if (cg == 0) {
                es[(size_t)bh * N + jt * 64 + jl] = p1;
                ed[(size_t)bh * N + jt * 64 + jl] = p2;
            }
        }
    }
}

// ---------------- K3a: softmax stats, h-merged (adj read ONCE per (b,i)) ----------
__global__ void k_stats(const float* __restrict__ adj, const float* __restrict__ esq,
                        const float* __restrict__ edq, const float* __restrict__ esv,
                        const float* __restrict__ edv, float* __restrict__ stats,
                        unsigned char* __restrict__ amask) {
    int pid = blockIdx.x;                 // b*N + i
    int b = pid >> 10, i = pid & 1023;
    int t = threadIdx.x;                  // 128 threads, 8 j each
    const float* arow = adj + (size_t)pid * N + t * 8;
    float4 a0 = *reinterpret_cast<const float4*>(arow);
    float4 a1 = *reinterpret_cast<const float4*>(arow + 4);
    float am[8] = {a0.x, a0.y, a0.z, a0.w, a1.x, a1.y, a1.z, a1.w};
    unsigned mb = 0;
    #pragma unroll
    for (int j = 0; j < 8; j++) mb |= (unsigned)(am[j] > 0.f) << j;
    amask[(size_t)pid * 128 + t] = (unsigned char)mb;

    __shared__ float red[2][2];
    __shared__ float red2[2][2];
    int w = t >> 6;
    for (int h = 0; h < H; h++) {
        int bh = b * H + h;
        float esqi = esq[(size_t)bh * N + i], esvi = esv[(size_t)bh * N + i];
        const float* edqr = edq + (size_t)bh * N + t * 8;
        const float* edvr = edv + (size_t)bh * N + t * 8;
        float4 q0 = *reinterpret_cast<const float4*>(edqr);
        float4 q1 = *reinterpret_cast<const float4*>(edqr + 4);
        float4 w0 = *reinterpret_cast<const float4*>(edvr);
        float4 w1 = *reinterpret_cast<const float4*>(edvr + 4);
        float edqv[8] = {q0.x, q0.y, q0.z, q0.w, q1.x, q1.y, q1.z, q1.w};
        float edvv[8] = {w0.x, w0.y, w0.z, w0.w, w1.x, w1.y, w1.z, w1.w};
        float eq[8], ev[8];
        float mq = -1e30f, mv = -1e30f;
        #pragma unroll
        for (int j = 0; j < 8; j++) {
            bool msk = (mb >> j) & 1;
            float q = esqi + edqv[j]; q = fmaxf(q, 0.2f * q);
            float v = esvi + edvv[j]; v = fmaxf(v, 0.2f * v);
            eq[j] = msk ? q : -1e30f;
            ev[j] = msk ? v : -1e30f;
            mq = fmaxf(mq, eq[j]); mv = fmaxf(mv, ev[j]);
        }
        for (int m = 32; m; m >>= 1) { mq = fmaxf(mq, __shfl_xor(mq, m)); mv = fmaxf(mv, __shfl_xor(mv, m)); }
        if ((t & 63) == 0) { red[w][0] = mq; red[w][1] = mv; }
        __syncthreads();
        mq = fmaxf(red[0][0], red[1][0]);
        mv = fmaxf(red[0][1], red[1][1]);
        float sq_ = 0.f, sv_ = 0.f;
        #pragma unroll
        for (int j = 0; j < 8; j++) { sq_ += __expf(eq[j] - mq); sv_ += __expf(ev[j] - mv); }
        for (int m = 32; m; m >>= 1) { sq_ += __shfl_xor(sq_, m); sv_ += __shfl_xor(sv_, m); }
        if ((t & 63) == 0) { red2[w][0] = sq_; red2[w][1] = sv_; }
        __syncthreads();
        if (t == 0) {
            int bid = bh * N + i;
            stats[bid] = mq;
            stats[BHN + bid] = red2[0][0] + red2[1][0];
            stats[2 * BHN + bid] = mv;
            stats[3 * BHN + bid] = red2[0][1] + red2[1][1];
        }
        __syncthreads();                  // WAR: red/red2 reused next h
    }
}

// ---------------- K3b: MFMA GAT aggregation; exp2-folded weights; full unroll ------
__global__ __launch_bounds__(512) void k_aggr(const unsigned char* __restrict__ amask,
        const unsigned short* __restrict__ hallT, const float* __restrict__ esq,
        const float* __restrict__ edq, const float* __restrict__ esv,
        const float* __restrict__ edv, const float* __restrict__ stats,
        float* __restrict__ outq, float* __restrict__ outv) {
    int f = blockIdx.x;
    int g = ((f & 7) << 7) | (f >> 3);        // bijective: 1024 = 8 x 128
    int b = g >> 7;
    int it = (g >> 2) & 31;
    int h = g & 3;
    int bh = b * H + h;
    int i0 = it * 32;
    int t = threadIdx.x;
    int lane = t & 63, wv = t >> 6;           // 0..7
    int team = wv >> 1;                       // j-quarter 0..3
    int mh = wv & 1;                          // i-half

    int i = i0 + mh * 16 + (lane & 15);
    int bi = bh * N + i;
    constexpr float L2E = 1.44269504f;
    float esq_i = esq[bi], esv_i = esv[bi];
    float cq2 = -fmaf(stats[bi],           L2E, __builtin_amdgcn_logf(stats[BHN + bi]));
    float cv2 = -fmaf(stats[2 * BHN + bi], L2E, __builtin_amdgcn_logf(stats[3 * BHN + bi]));
    const unsigned char* mrow = amask + (size_t)(b * N + i) * 128;
    const float* edqrow = edq + (size_t)bh * N;
    const float* edvrow = edv + (size_t)bh * N;
    int klo = lane >> 4;
    const unsigned short* bbq = hallT
        + ((size_t)(bh * 128 + (lane & 15))) * 1024 + klo * 8;
    const unsigned short* bbv = bbq + (size_t)64 * 1024;

    f32x4 accq[4] = {}, accv[4] = {};
    int jbase = team * 256;
    #pragma unroll
    for (int jj = 0; jj < 8; jj++) {
        int j0 = jbase + jj * 32;
        unsigned mword = *reinterpret_cast<const unsigned*>(mrow + (j0 >> 3));
        float4 q0 = *reinterpret_cast<const float4*>(edqrow + j0 + klo * 8);
        float4 q1 = *reinterpret_cast<const float4*>(edqrow + j0 + klo * 8 + 4);
        float4 v0 = *reinterpret_cast<const float4*>(edvrow + j0 + klo * 8);
        float4 v1 = *reinterpret_cast<const float4*>(edvrow + j0 + klo * 8 + 4);
        float eq[8] = {q0.x, q0.y, q0.z, q0.w, q1.x, q1.y, q1.z, q1.w};
        float ev[8] = {v0.x, v0.y, v0.z, v0.w, v1.x, v1.y, v1.z, v1.w};
        union { uint4 u4; short8 s8; } pq_, pv_;
        unsigned* uq = reinterpret_cast<unsigned*>(&pq_.u4);
        unsigned* uv = reinterpret_cast<unsigned*>(&pv_.u4);
        #pragma unroll
        for (int pu = 0; pu < 4; pu++) {
            unsigned wq0, wq1, wv0, wv1;
            {
                int u = pu * 2;
                bool on = (mword >> (klo * 8 + u)) & 1;
                float q = esq_i + eq[u]; q = fmaxf(q, 0.2f * q);
                float v = esv_i + ev[u]; v = fmaxf(v, 0.2f * v);
                wq0 = on ? __float_as_uint(__builtin_amdgcn_exp2f(fmaf(q, L2E, cq2))) : 0u;
                wv0 = on ? __float_as_uint(__builtin_amdgcn_exp2f(fmaf(v, L2E, cv2))) : 0u;
            }
            {
                int u = pu * 2 + 1;
                bool on = (mword >> (klo * 8 + u)) & 1;
                float q = esq_i + eq[u]; q = fmaxf(q, 0.2f * q);
                float v = esv_i + ev[u]; v = fmaxf(v, 0.2f * v);
                wq1 = on ? __float_as_uint(__builtin_amdgcn_exp2f(fmaf(q, L2E, cq2))) : 0u;
                wv1 = on ? __float_as_uint(__builtin_amdgcn_exp2f(fmaf(v, L2E, cv2))) : 0u;
            }
            uq[pu] = (wq0 >> 16) | (wq1 & 0xFFFF0000u);   // trunc bf16 pair
            uv[pu] = (wv0 >> 16) | (wv1 & 0xFFFF0000u);
        }
        short8 afq = pq_.s8, afv = pv_.s8;
        #pragma unroll
        for (int nt = 0; nt < 4; nt++) {
            short8 bq = *reinterpret_cast<const short8*>(bbq + j0 + nt * 16384);
            accq[nt] = __builtin_amdgcn_mfma_f32_16x16x32_bf16(afq, bq, accq[nt], 0, 0, 0);
            short8 bv = *reinterpret_cast<const short8*>(bbv + j0 + nt * 16384);
            accv[nt] = __builtin_amdgcn_mfma_f32_16x16x32_bf16(afv, bv, accv[nt], 0, 0, 0);
        }
    }

    // 2-stage team combine: slots = (team>>1)*2 + mh, 4 x 8KB = 32KB
    __shared__ __align__(16) float red[8192];
    int slot = (team >> 1) * 2 + mh;
    float* buf = red + slot * 2048;
    __syncthreads();
    if (team & 1) {                           // teams 1,3 write
        #pragma unroll
        for (int k = 0; k < 4; k++) {
            *reinterpret_cast<f32x4*>(&buf[(k * 64 + lane) * 4])       = accq[k];
            *reinterpret_cast<f32x4*>(&buf[((k + 4) * 64 + lane) * 4]) = accv[k];
        }
    }
    __syncthreads();
    if (!(team & 1)) {                        // teams 0,2 add partner
        #pragma unroll
        for (int k = 0; k < 4; k++) {
            f32x4 pq = *reinterpret_cast<const f32x4*>(&buf[(k * 64 + lane) * 4]);
            f32x4 pv = *reinterpret_cast<const f32x4*>(&buf[((k + 4) * 64 + lane) * 4]);
            accq[k] += pq; accv[k] += pv;
        }
    }
    __syncthreads();
    if (team == 2) {                          // team 2 writes to slots 0,1
        float* d2 = red + mh * 2048;
        #pragma unroll
        for (int k = 0; k < 4; k++) {
            *reinterpret_cast<f32x4*>(&d2[(k * 64 + lane) * 4])       = accq[k];
            *reinterpret_cast<f32x4*>(&d2[((k + 4) * 64 + lane) * 4]) = accv[k];
        }
    }
    __syncthreads();
    if (team == 0) {
        float* s2 = red + mh * 2048;
        #pragma unroll
        for (int nt = 0; nt < 4; nt++) {
            f32x4 pq = *reinterpret_cast<const f32x4*>(&s2[(nt * 64 + lane) * 4]);
            f32x4 pv = *reinterpret_cast<const f32x4*>(&s2[((nt + 4) * 64 + lane) * 4]);
            #pragma unroll
            for (int r = 0; r < 4; r++) {
                int irow = i0 + mh * 16 + (lane >> 4) * 4 + r;
                int e = nt * 16 + (lane & 15);
                outq[(size_t)(b * N + irow) * 256 + h * 64 + e] = accq[nt][r] + pq[r];
                outv[(size_t)(b * N + irow) * 256 + h * 64 + e] = accv[nt][r] + pv[r];
            }
        }
    }
}

// ---------------- K4: expmap0; emits qh/ql (bf16 hi/lo), sq, isr, val ----------------
__global__ void k_expmap(const float* __restrict__ outq, const float* __restrict__ outv,
                         unsigned short* __restrict__ qh, unsigned short* __restrict__ ql,
                         float* __restrict__ sq, float* __restrict__ isr,
                         float* __restrict__ val) {
    int p = blockIdx.x, t = threadIdx.x;
    int h = t >> 6, e = t & 63;
    float v = outq[(size_t)p * HD + t];
    float ss = v * v;
    for (int m = 32; m; m >>= 1) ss += __shfl_xor(ss, m);
    float n = fmaxf(sqrtf(ss), EPSF);
    float tn = tanhf(n);
    float qv = v * (tn / n);
    short hs, ls; tsplit(qv, hs, ls);
    qh[((size_t)p << 8) + t] = (unsigned short)hs;
    ql[((size_t)p << 8) + t] = (unsigned short)ls;
    if (e == 0) {
        float s = tn * tn;
        sq[h * BN + p] = s;
        isr[h * BN + p] = __builtin_amdgcn_rcpf(1.f - s);
    }

    float vv = outv[(size_t)p * HDV + t];
    float s2 = vv * vv;
    for (int m = 32; m; m >>= 1) s2 += __shfl_xor(s2, m);
    __shared__ float part[4];
    if (e == 0) part[h] = s2;
    __syncthreads();
    float tot = part[0] + part[1] + part[2] + part[3];
    float nv = fmaxf(sqrtf(tot), EPSF);
    float sclv = tanhf(nv) / nv;
    val[(size_t)p * HDV + t] = vv * sclv;
}

// ---------------- K5: MFMA pair-dist, barrier-free; B-side hi-only (2 MFMA) --------
// reshape(-1,B,N,N) closed form: h=m2%4, m=(n2%4)*256+m2/4, n=(b2*256+n2/4)%1024, b=2a+b2/4
__global__ __launch_bounds__(256) void k_att(const unsigned short* __restrict__ qh,
        const unsigned short* __restrict__ ql, const float* __restrict__ sq,
        const float* __restrict__ isr, const float* __restrict__ rr,
        const float* __restrict__ tt, float* __restrict__ m_out) {
    int f = blockIdx.x;
    int g = ((f & 7) << 7) | (f >> 3);        // bijective 1024
    int b2 = g >> 7;
    int rem = g & 127;
    int c = rem >> 5, h = (rem >> 3) & 3, kc = (rem >> 1) & 3, xh = rem & 1;
    int t = threadIdx.x;
    int l = t & 63, w = t >> 6;
    int klo = l >> 4;

    int nstart = (b2 * 256 + kc * 64) & 1023;
    int mstart = c * 256 + xh * 128;

    float tacc[8][4] = {};

    #pragma unroll
    for (int a = 0; a < 4; a++) {
        int b = 2 * a + (b2 >> 2);
        size_t xbase = ((size_t)(b * N + nstart + w * 16 + (l & 15)) << 8) + h * 64 + klo * 8;
        short8 Ah[2], Al[2];
        #pragma unroll
        for (int kk = 0; kk < 2; kk++) {
            Ah[kk] = *reinterpret_cast<const short8*>(qh + xbase + kk * 32);
            Al[kk] = *reinterpret_cast<const short8*>(ql + xbase + kk * 32);
        }
        float ra = rr[a], ta = tt[a];
        float c1 = 2.f * ta;                       // ln2*log2e == 1
        float c0 = c1 * ra * 1.44269504f;          // 2*r*t*log2e
        float sxr[4], ixr[4];
        #pragma unroll
        for (int r = 0; r < 4; r++) {
            int gx = h * BN + b * N + nstart + w * 16 + (l >> 4) * 4 + r;
            sxr[r] = sq[gx];
            ixr[r] = 2.f * isr[gx];
        }
        size_t ybase = ((size_t)(b * N + mstart + (l & 15)) << 8) + h * 64 + klo * 8;
        #pragma unroll
        for (int nt = 0; nt < 8; nt++) {
            size_t yb = ybase + ((size_t)(nt * 16) << 8);
            f32x4 acc = {};
            #pragma unroll
            for (int kk = 0; kk < 2; kk++) {
                short8 Bh = *reinterpret_cast<const short8*>(qh + yb + kk * 32);
                acc = __builtin_amdgcn_mfma_f32_16x16x32_bf16(Ah[kk], Bh, acc, 0, 0, 0);
                acc = __builtin_amdgcn_mfma_f32_16x16x32_bf16(Al[kk], Bh, acc, 0, 0, 0);
            }
            int gy = h * BN + b * N + mstart + nt * 16 + (l & 15);
            float sy = sq[gy];
            float iy = isr[gy];
            #pragma unroll
            for (int r = 0; r < 4; r++) {
                float diff = fmaxf(fmaf(-2.f, acc[r], sxr[r] + sy), 0.f);
                float ixy = fminf(ixr[r] * iy, 2e7f);          // 2/max(den,1e-7)
                float z = fmaxf(fmaf(diff, ixy, 1.f), 1.f + EPSF);
                float s_ = z + __builtin_amdgcn_sqrtf(fmaf(z, z, -1.f));   // e^dist
                float l2 = __builtin_amdgcn_logf(s_);                      // log2
                float ex = __builtin_amdgcn_exp2f(fmaf(-c1, l2, c0));      // e^{2u}
                float rc = __builtin_amdgcn_rcpf(ex + 1.f);
                tacc[nt][r] += fmaf(-2.f, rc, 1.f);            // tanh(u), NaN-safe
            }
        }
    }
    // write-out (scrambled reshape positions)
    #pragma unroll
    for (int nt = 0; nt < 8; nt++) {
        #pragma unroll
        for (int r = 0; r < 4; r++) {
            int n_local = w * 16 + (l >> 4) * 4 + r;
            int n2 = c + 4 * (kc * 64 + n_local);
            int mloc = xh * 128 + nt * 16 + (l & 15);
            int m2 = 4 * mloc + h;
            m_out[((size_t)b2 << 20) + ((size_t)n2 << 10) + m2] = 0.25f * tacc[nt][r];
        }
    }
}

// ---------------- K6: in-place symmetrize on d_out att region ----------------
__global__ void k_sym(float* __restrict__ m) {
    int ti = blockIdx.x, tj = blockIdx.y, b = blockIdx.z;
    if (ti > tj) return;
    __shared__ float A[32][33], Bt[32][33];
    int t = threadIdx.x;
    int r = t >> 3, c4 = (t & 7) * 4;
    size_t baseA = ((size_t)b << 20) + (size_t)(ti * 32) * N + tj * 32;
    size_t baseB = ((size_t)b << 20) + (size_t)(tj * 32) * N + ti * 32;
    float4 ua = *reinterpret_cast<const float4*>(m + baseA + (size_t)r * N + c4);
    float4 ub = *reinterpret_cast<const float4*>(m + baseB + (size_t)r * N + c4);
    A[r][c4 + 0] = ua.x; A[r][c4 + 1] = ua.y; A[r][c4 + 2] = ua.z; A[r][c4 + 3] = ua.w;
    Bt[r][c4 + 0] = ub.x; Bt[r][c4 + 1] = ub.y; Bt[r][c4 + 2] = ub.z; Bt[r][c4 + 3] = ub.w;
    __syncthreads();
    for (int u = 0; u < 4; u++) {
        int cc = c4 + u;
        float oa = 0.5f * (A[r][cc] + Bt[cc][r]);
        float ob = 0.5f * (Bt[r][cc] + A[cc][r]);
        m[baseA + (size_t)r * N + cc] = oa;
        m[baseB + (size_t)r * N + cc] = ob;
    }
}

extern "C" void kernel_launch(void* const* d_in, const int* in_sizes, int n_in,
                              void* d_out, int out_size, void* d_ws, size_t ws_size,
                              hipStream_t stream) {
    const float* x   = (const float*)d_in[0];
    const float* adj = (const float*)d_in[1];
    const float* Wq  = (const float*)d_in[3];
    const float* aqs = (const float*)d_in[4];
    const float* aqd = (const float*)d_in[5];
    const float* Wv  = (const float*)d_in[6];
    const float* avs = (const float*)d_in[7];
    const float* avd = (const float*)d_in[8];
    const float* rr  = (const float*)d_in[9];
    const float* tt  = (const float*)d_in[10];

    float* ws = (float*)d_ws;
    float* s     = ws;                            // 8192 (unused slot, kept for layout)
    float* Wc    = s + BN;                        // 131072 f32
    float* hall  = Wc + 256 * COLS;               // 4194304 f32 (16 MB)
    float* esq   = hall + (size_t)BN * COLS;      // 32768 x4
    float* edq   = esq + BHN;
    float* esv   = edq + BHN;
    float* edv   = esv + BHN;
    float* stats = edv + BHN;                     // 4*BHN
    float* outq  = stats + 4 * BHN;               // 2097152
    float* outv  = outq + (size_t)BN * HD;        // 2097152
    float* sq    = outv + (size_t)BN * HDV;       // 32768
    unsigned short* hallT = (unsigned short*)(sq + H * BN);   // BN*COLS bf16 = 8 MB
    unsigned char* amask = (unsigned char*)(hallT + (size_t)BN * COLS); // 1 MB
    size_t need = (size_t)((char*)(amask + (size_t)BN * 128) - (char*)ws);
    if (ws_size < need) return;                   // ws too small: bail visibly

    // qh/ql/isr alias the hall region (dead after k_hT reads it; k_expmap runs later)
    unsigned short* qh = (unsigned short*)hall;
    unsigned short* ql = qh + (size_t)BN * 256;
    float* isr = (float*)(ql + (size_t)BN * 256);

    float* val  = (float*)d_out;
    float* matt = (float*)d_out + (size_t)BN * HDV;

    k_wcat<<<(256 * COLS) / 256, 256, 0, stream>>>(Wq, Wv, Wc);
    k_gemm<<<dim3(BN / 64, COLS / 64), 256, 0, stream>>>(x, Wc, hall);
    k_hT<<<dim3(16, H, B), 256, 0, stream>>>(hall, aqs, aqd, avs, avd,
                                             hallT, esq, edq, esv, edv);
    k_stats<<<BN, 128, 0, stream>>>(adj, esq, edq, esv, edv, stats, amask);
    k_aggr<<<1024, 512, 0, stream>>>(amask, hallT, esq, edq, esv, edv, stats, outq, outv);
    k_expmap<<<BN, 256, 0, stream>>>(outq, outv, qh, ql, sq, isr, val);
    k_att<<<1024, 256, 0, stream>>>(qh, ql, sq, isr, rr, tt, matt);
    k_sym<<<dim3(32, 32, 8), 256, 0, stream>>>(matt);
}